// Round 16
// baseline (624.014 us; speedup 1.0000x reference)
//
#include <hip/hip_runtime.h>
#include <stdint.h>

#define NVN 100000
#define NCN 50000
#define NE  800000
#define H   128

typedef __attribute__((ext_vector_type(8))) short bf16x8;
typedef __attribute__((ext_vector_type(4))) float f32x4;

static __device__ __forceinline__ float wredsum(float v) {
#pragma unroll
  for (int off = 32; off > 0; off >>= 1) v += __shfl_xor(v, off, 64);
  return v;
}
static __device__ __forceinline__ float sigmoidf(float x) { return 1.0f / (1.0f + __expf(-x)); }
static __device__ __forceinline__ unsigned short f2bf(float f) {
  unsigned int u = __float_as_uint(f);
  return (unsigned short)((u + 0x7FFFu + ((u >> 16) & 1u)) >> 16);  // RNE
}
static __device__ __forceinline__ short2 splitbf(float f) {
  unsigned short h = f2bf(f);
  float hf = __uint_as_float(((unsigned int)h) << 16);
  short2 r;
  r.x = (short)h;
  r.y = (short)f2bf(f - hf);
  return r;
}

// ---------------- init: h = LN(relu(x @ W + b)), writes f32 master + bf16 shadow ----------------
__global__ __launch_bounds__(256) void k_init_var(const float* __restrict__ xv,
    const float* __restrict__ w, const float* __restrict__ b,
    const float* __restrict__ g, const float* __restrict__ bb,
    float* __restrict__ hv, unsigned short* __restrict__ hb) {
  int wid = (blockIdx.x * 256 + threadIdx.x) >> 6;
  int lane = threadIdx.x & 63;
  if (wid >= NVN) return;
  float x0 = xv[wid*4+0], x1 = xv[wid*4+1], x2 = xv[wid*4+2], x3 = xv[wid*4+3];
  int c0 = lane, c1 = lane + 64;
  float v0 = b[c0] + x0*w[c0] + x1*w[H+c0] + x2*w[2*H+c0] + x3*w[3*H+c0];
  float v1 = b[c1] + x0*w[c1] + x1*w[H+c1] + x2*w[2*H+c1] + x3*w[3*H+c1];
  v0 = fmaxf(v0, 0.f); v1 = fmaxf(v1, 0.f);
  float mu = wredsum(v0 + v1) * (1.0f/H);
  float d0 = v0 - mu, d1 = v1 - mu;
  float var = wredsum(d0*d0 + d1*d1) * (1.0f/H);
  float r = rsqrtf(var + 1e-5f);
  float o0 = d0*r*g[c0] + bb[c0], o1 = d1*r*g[c1] + bb[c1];
  hv[(size_t)wid*H + c0] = o0;  hv[(size_t)wid*H + c1] = o1;
  hb[(size_t)wid*H + c0] = f2bf(o0);  hb[(size_t)wid*H + c1] = f2bf(o1);
}

__global__ __launch_bounds__(256) void k_init_con(const float* __restrict__ xc,
    const float* __restrict__ w, const float* __restrict__ b,
    const float* __restrict__ g, const float* __restrict__ bb,
    float* __restrict__ hc, unsigned short* __restrict__ hb) {
  int wid = (blockIdx.x * 256 + threadIdx.x) >> 6;
  int lane = threadIdx.x & 63;
  if (wid >= NCN) return;
  float x = xc[wid];
  int c0 = lane, c1 = lane + 64;
  float v0 = fmaxf(b[c0] + x*w[c0], 0.f);
  float v1 = fmaxf(b[c1] + x*w[c1], 0.f);
  float mu = wredsum(v0 + v1) * (1.0f/H);
  float d0 = v0 - mu, d1 = v1 - mu;
  float var = wredsum(d0*d0 + d1*d1) * (1.0f/H);
  float r = rsqrtf(var + 1e-5f);
  float o0 = d0*r*g[c0] + bb[c0], o1 = d1*r*g[c1] + bb[c1];
  hc[(size_t)wid*H + c0] = o0;  hc[(size_t)wid*H + c1] = o1;
  hb[(size_t)wid*H + c0] = f2bf(o0);  hb[(size_t)wid*H + c1] = f2bf(o1);
}

// ---------------- weight fusion ----------------
__global__ void k_fuse_w(const float* __restrict__ wm, const float* __restrict__ wu,
                         float* __restrict__ wf) {
  int idx = blockIdx.x*256 + threadIdx.x;   // 16384
  int i = idx >> 7, j = idx & 127;
  float a = 0.f;
  for (int k = 0; k < H; ++k) a = fmaf(wm[i*H+k], wu[k*H+j], a);
  wf[idx] = a;
}
__global__ void k_fuse_b(const float* __restrict__ bm, const float* __restrict__ wu,
                         float* __restrict__ bf) {
  int j = threadIdx.x;
  float a = 0.f;
  for (int k = 0; k < H; ++k) a = fmaf(bm[k], wu[k*H+j], a);
  bf[j] = a;
}

// ---------------- weight permutation into MFMA B-fragment order, hi+lo split ----------------
__global__ __launch_bounds__(256) void k_perm2(const float* __restrict__ W,
    unsigned short* __restrict__ Whi, unsigned short* __restrict__ Wlo, int K) {
  int idx = blockIdx.x*256 + threadIdx.x;
  if (idx >= K*H) return;
  int j = idx & 7, lane = (idx >> 3) & 63, ct = (idx >> 9) & 7, kb = idx >> 12;
  int k = kb*32 + (lane >> 4)*8 + j, c = ct*16 + (lane & 15);
  float w = W[k*H + c];
  unsigned short h = f2bf(w);
  float hf = __uint_as_float(((unsigned int)h) << 16);
  Whi[idx] = h;
  Wlo[idx] = f2bf(w - hf);
}

// ---------------- CSR build ----------------
__global__ void k_count(const int* __restrict__ dc, const int* __restrict__ dv,
                        int* __restrict__ cnt_c, int* __restrict__ cnt_v) {
  for (int e = blockIdx.x*blockDim.x + threadIdx.x; e < NE; e += gridDim.x*blockDim.x) {
    atomicAdd(&cnt_c[dc[e]], 1);
    atomicAdd(&cnt_v[dv[e]], 1);
  }
}
__global__ __launch_bounds__(256) void k_scan1(const int* __restrict__ in, int* __restrict__ out,
                                               int* __restrict__ aux, int n) {
  __shared__ int s[256];
  int t = threadIdx.x, i = blockIdx.x*256 + t;
  int v = (i < n) ? in[i] : 0;
  s[t] = v; __syncthreads();
  for (int off = 1; off < 256; off <<= 1) {
    int x = (t >= off) ? s[t - off] : 0;
    __syncthreads();
    s[t] += x;
    __syncthreads();
  }
  if (i < n) out[i] = s[t] - v;
  if (t == 255) aux[blockIdx.x] = s[255];
}
__global__ __launch_bounds__(1024) void k_scan2(int* __restrict__ aux, int nb) {
  __shared__ int s[1024];
  int t = threadIdx.x;
  int v = (t < nb) ? aux[t] : 0;
  s[t] = v; __syncthreads();
  for (int off = 1; off < 1024; off <<= 1) {
    int x = (t >= off) ? s[t-off] : 0;
    __syncthreads();
    s[t] += x;
    __syncthreads();
  }
  if (t < nb) aux[t] = s[t] - v;
}
__global__ __launch_bounds__(256) void k_scan3(int* __restrict__ out, const int* __restrict__ aux,
                                               int n, int total) {
  int i = blockIdx.x*256 + threadIdx.x;
  if (i < n) out[i] += aux[blockIdx.x];
  if (i == 0) out[n] = total;
}
// scatter with atomicExch data writes: atomics execute at the shared cache level,
// so scattered 4B writes merge there instead of each costing a full line at HBM.
__global__ void k_scatter(const int* __restrict__ sc, const int* __restrict__ dc,
                          const int* __restrict__ sv, const int* __restrict__ dv,
                          const int* __restrict__ off_c, int* __restrict__ cur_c, int* __restrict__ lst_c,
                          const int* __restrict__ off_v, int* __restrict__ cur_v, int* __restrict__ lst_v) {
  for (int e = blockIdx.x*blockDim.x + threadIdx.x; e < NE; e += gridDim.x*blockDim.x) {
    int d = dc[e]; int p = atomicAdd(&cur_c[d], 1); (void)atomicExch(&lst_c[off_c[d] + p], sc[e]);
    d = dv[e];     p = atomicAdd(&cur_v[d], 1);     (void)atomicExch(&lst_v[off_v[d] + p], sv[e]);
  }
}

// ---------------- lane-packed gather: 16 lanes/row-octet x 4 edge slots, 16B/lane ----------------
__global__ __launch_bounds__(256) void k_gather_bf(const unsigned int* __restrict__ tab,
    const int* __restrict__ off, const int* __restrict__ lst,
    float* __restrict__ out, int n) {
  int wid = (blockIdx.x * 256 + threadIdx.x) >> 6;
  int lane = threadIdx.x & 63;
  if (wid >= n) return;
  int s0 = off[wid], s1 = off[wid+1];
  const int grp = lane >> 4, c16 = lane & 15;
  float acc[8];
#pragma unroll
  for (int j = 0; j < 8; ++j) acc[j] = 0.f;
#pragma unroll 2
  for (int p = s0 + grp; p < s1; p += 4) {
    int idx = lst[p];
    uint4 u = *(const uint4*)(tab + (size_t)idx*64 + c16*4);
    acc[0] += __uint_as_float(u.x << 16);
    acc[1] += __uint_as_float(u.x & 0xFFFF0000u);
    acc[2] += __uint_as_float(u.y << 16);
    acc[3] += __uint_as_float(u.y & 0xFFFF0000u);
    acc[4] += __uint_as_float(u.z << 16);
    acc[5] += __uint_as_float(u.z & 0xFFFF0000u);
    acc[6] += __uint_as_float(u.w << 16);
    acc[7] += __uint_as_float(u.w & 0xFFFF0000u);
  }
#pragma unroll
  for (int j = 0; j < 8; ++j) {
    acc[j] += __shfl_xor(acc[j], 16, 64);
    acc[j] += __shfl_xor(acc[j], 32, 64);
  }
  if (lane < 16) {
    float inv = 1.0f / ((float)(s1 - s0) + 1e-6f);
    float* op = out + (size_t)wid*H + c16*8;
    *(float4*)(op)     = make_float4(acc[0]*inv, acc[1]*inv, acc[2]*inv, acc[3]*inv);
    *(float4*)(op + 4) = make_float4(acc[4]*inv, acc[5]*inv, acc[6]*inv, acc[7]*inv);
  }
}

// ====== mega-fused: matmul1 -> LDS park -> SIMT LN -> gate matmul2 -> blend ======
// 2 waves / 128 threads / 32 rows per block; LDS 16.9KB.
template<int EPI>
__global__ __launch_bounds__(128) void k_mleg(
    const float* __restrict__ A,
    const unsigned short* __restrict__ Wph, const unsigned short* __restrict__ Wpl,
    const int* __restrict__ cnt, const float* __restrict__ xc,
    const float* __restrict__ vb, const float* __restrict__ wcl,
    const float* __restrict__ badd, const float* __restrict__ lng,
    const float* __restrict__ lnb,
    const unsigned short* __restrict__ Gph, const float* __restrict__ gb,
    float* __restrict__ Hm, unsigned short* __restrict__ Hb, int n) {
  __shared__ float lds[32][132];               // 16.9KB park buffer
  const int wv = threadIdx.x >> 6, lane = threadIdx.x & 63;
  const int rbase = blockIdx.x*32 + wv*16;
  if (rbase >= n) return;
  const int g = lane >> 4, c15 = lane & 15;
  int arow = rbase + c15; if (arow > n-1) arow = n-1;

  // ---- prefetch A1 = Hm own rows (raw f32), latency hides under matmul1 + LN ----
  const float* Ar1 = Hm + (size_t)arow*H + g*8;
  float4 pf[8];
#pragma unroll
  for (int kb = 0; kb < 4; ++kb) {
    pf[2*kb]   = *(const float4*)(Ar1 + kb*32);
    pf[2*kb+1] = *(const float4*)(Ar1 + kb*32 + 4);
  }

  // ---- matmul1: A @ W (split both operands, 3 MFMA) ----
  {
    const float* Ar = A + (size_t)arow*H + g*8;
    bf16x8 ahi[4], alo[4];
#pragma unroll
    for (int kb = 0; kb < 4; ++kb) {
      float4 p0 = *(const float4*)(Ar + kb*32);
      float4 p1 = *(const float4*)(Ar + kb*32 + 4);
      bf16x8 h, l;
      short2 s;
      s = splitbf(p0.x); h[0] = s.x; l[0] = s.y;
      s = splitbf(p0.y); h[1] = s.x; l[1] = s.y;
      s = splitbf(p0.z); h[2] = s.x; l[2] = s.y;
      s = splitbf(p0.w); h[3] = s.x; l[3] = s.y;
      s = splitbf(p1.x); h[4] = s.x; l[4] = s.y;
      s = splitbf(p1.y); h[5] = s.x; l[5] = s.y;
      s = splitbf(p1.z); h[6] = s.x; l[6] = s.y;
      s = splitbf(p1.w); h[7] = s.x; l[7] = s.y;
      ahi[kb] = h; alo[kb] = l;
    }
    const bf16x8* Bph = (const bf16x8*)Wph;
    const bf16x8* Bpl = (const bf16x8*)Wpl;
    f32x4 zero = {0.f, 0.f, 0.f, 0.f};
    f32x4 acc[8];
#pragma unroll
    for (int ct = 0; ct < 8; ++ct) acc[ct] = zero;
#pragma unroll
    for (int kb = 0; kb < 4; ++kb)
#pragma unroll
      for (int ct = 0; ct < 8; ++ct) {
        bf16x8 bh = Bph[(kb*8+ct)*64 + lane];
        bf16x8 bl = Bpl[(kb*8+ct)*64 + lane];
        acc[ct] = __builtin_amdgcn_mfma_f32_16x16x32_bf16(ahi[kb], bh, acc[ct], 0, 0, 0);
        acc[ct] = __builtin_amdgcn_mfma_f32_16x16x32_bf16(alo[kb], bh, acc[ct], 0, 0, 0);
        acc[ct] = __builtin_amdgcn_mfma_f32_16x16x32_bf16(ahi[kb], bl, acc[ct], 0, 0, 0);
      }
    // park pre-activation into LDS (wave-local rows)
#pragma unroll
    for (int r = 0; r < 4; ++r)
#pragma unroll
      for (int ct = 0; ct < 8; ++ct)
        lds[wv*16 + g*4 + r][ct*16 + c15] = acc[ct][r];
  }

  // ---- proven SIMT LN epilogue; full blocks fully unrolled ----
  {
    float vb0 = vb[lane], vb1 = vb[lane+64];
    float lg0 = lng[lane], lg1 = lng[lane+64];
    float lb0 = lnb[lane], lb1 = lnb[lane+64];
    float wc0 = 0.f, wc1 = 0.f, ba0 = 0.f, ba1 = 0.f;
    if constexpr (EPI == 0) {
      wc0 = wcl[lane]; wc1 = wcl[lane+64];
      ba0 = badd[lane]; ba1 = badd[lane+64];
    }
    auto lnrow = [&](int row, int dst) {
      float cf = (float)cnt[dst];
      float scale = cf / (cf + 1e-6f);
      float v0 = lds[row][lane]     + scale*vb0;
      float v1 = lds[row][lane+64]  + scale*vb1;
      if constexpr (EPI == 0) {
        float clue = xc[dst];
        v0 += clue*wc0 + ba0;
        v1 += clue*wc1 + ba1;
      }
      v0 = fmaxf(v0, 0.f); v1 = fmaxf(v1, 0.f);
      float mu = wredsum(v0 + v1) * (1.0f/H);
      float d0 = v0 - mu, d1 = v1 - mu;
      float var = wredsum(d0*d0 + d1*d1) * (1.0f/H);
      float r = rsqrtf(var + 1e-5f);
      lds[row][lane]      = d0*r*lg0 + lb0;
      lds[row][lane + 64] = d1*r*lg1 + lb1;
    };
    const int blk = blockIdx.x*32;
    if (blk + 32 <= n) {
#pragma unroll
      for (int i = 0; i < 16; ++i) lnrow(wv*16 + i, blk + wv*16 + i);
    } else {
      for (int i = 0; i < 16; ++i) {
        int dst = blk + wv*16 + i;
        if (dst >= n) break;
        lnrow(wv*16 + i, dst);
      }
    }
  }

  // ---- matmul2: [Hm(prefetched) | c_new(LDS)] @ G (A split, B hi-only) + sigmoid gate ----
  {
    bf16x8 ahi[8], alo[8];
#pragma unroll
    for (int kb = 0; kb < 4; ++kb) {
      float4 p0 = pf[2*kb];
      float4 p1 = pf[2*kb+1];
      bf16x8 h, l;
      short2 s;
      s = splitbf(p0.x); h[0] = s.x; l[0] = s.y;
      s = splitbf(p0.y); h[1] = s.x; l[1] = s.y;
      s = splitbf(p0.z); h[2] = s.x; l[2] = s.y;
      s = splitbf(p0.w); h[3] = s.x; l[3] = s.y;
      s = splitbf(p1.x); h[4] = s.x; l[4] = s.y;
      s = splitbf(p1.y); h[5] = s.x; l[5] = s.y;
      s = splitbf(p1.z); h[6] = s.x; l[6] = s.y;
      s = splitbf(p1.w); h[7] = s.x; l[7] = s.y;
      ahi[kb] = h; alo[kb] = l;
    }
    const float* Ar2 = &lds[wv*16 + c15][0];               // c_new (LDS, own wave rows)
#pragma unroll
    for (int kb = 4; kb < 8; ++kb) {
      float4 p0 = *(const float4*)(Ar2 + (kb-4)*32 + g*8);
      float4 p1 = *(const float4*)(Ar2 + (kb-4)*32 + g*8 + 4);
      bf16x8 h, l;
      short2 s;
      s = splitbf(p0.x); h[0] = s.x; l[0] = s.y;
      s = splitbf(p0.y); h[1] = s.x; l[1] = s.y;
      s = splitbf(p0.z); h[2] = s.x; l[2] = s.y;
      s = splitbf(p0.w); h[3] = s.x; l[3] = s.y;
      s = splitbf(p1.x); h[4] = s.x; l[4] = s.y;
      s = splitbf(p1.y); h[5] = s.x; l[5] = s.y;
      s = splitbf(p1.z); h[6] = s.x; l[6] = s.y;
      s = splitbf(p1.w); h[7] = s.x; l[7] = s.y;
      ahi[kb] = h; alo[kb] = l;
    }
    const bf16x8* Bph = (const bf16x8*)Gph;
    f32x4 zero = {0.f, 0.f, 0.f, 0.f};
    f32x4 acc[8];
#pragma unroll
    for (int ct = 0; ct < 8; ++ct) acc[ct] = zero;
#pragma unroll
    for (int kb = 0; kb < 8; ++kb)
#pragma unroll
      for (int ct = 0; ct < 8; ++ct) {
        bf16x8 bh = Bph[(kb*8+ct)*64 + lane];
        acc[ct] = __builtin_amdgcn_mfma_f32_16x16x32_bf16(ahi[kb], bh, acc[ct], 0, 0, 0);
        acc[ct] = __builtin_amdgcn_mfma_f32_16x16x32_bf16(alo[kb], bh, acc[ct], 0, 0, 0);
      }
    float gbv[8];
#pragma unroll
    for (int ct = 0; ct < 8; ++ct) gbv[ct] = gb[ct*16 + c15];
#pragma unroll
    for (int r = 0; r < 4; ++r) {
      int rg = rbase + g*4 + r;
      if (rg >= n) continue;
      int row = wv*16 + g*4 + r;
      float* hp = Hm + (size_t)rg*H + c15;
      unsigned short* hbp = Hb + (size_t)rg*H + c15;
#pragma unroll
      for (int ct = 0; ct < 8; ++ct) {
        float gg = sigmoidf(acc[ct][r] + gbv[ct]);
        float nv = lds[row][ct*16 + c15];
        float ov = hp[ct*16];
        float res = gg*nv + (1.f - gg)*ov;
        hp[ct*16] = res;
        hbp[ct*16] = f2bf(res);
      }
    }
  }
}

extern "C" void kernel_launch(void* const* d_in, const int* in_sizes, int n_in,
                              void* d_out, int out_size, void* d_ws, size_t ws_size,
                              hipStream_t stream) {
  const float* x_var   = (const float*)d_in[0];
  const float* x_con   = (const float*)d_in[1];
  const int*   evc_src = (const int*)d_in[2];
  const int*   evc_dst = (const int*)d_in[3];
  const int*   ecv_src = (const int*)d_in[4];
  const int*   ecv_dst = (const int*)d_in[5];
  const float* vproj_w = (const float*)d_in[6];
  const float* vproj_b = (const float*)d_in[7];
  const float* cproj_w = (const float*)d_in[8];
  const float* cproj_b = (const float*)d_in[9];
  const float* wmsg    = (const float*)d_in[10];
  const float* bmsg    = (const float*)d_in[11];
  const float* wupd    = (const float*)d_in[12];
  const float* bupd    = (const float*)d_in[13];
  const float* v2c_ln_g = (const float*)d_in[14];
  const float* v2c_ln_b = (const float*)d_in[15];
  const float* wc2v    = (const float*)d_in[16];
  const float* bc2v    = (const float*)d_in[17];
  const float* c2v_ln_g = (const float*)d_in[18];
  const float* c2v_ln_b = (const float*)d_in[19];
  const float* vgate_w = (const float*)d_in[20];
  const float* vgate_b = (const float*)d_in[21];
  const float* cgate_w = (const float*)d_in[22];
  const float* cgate_b = (const float*)d_in[23];
  const float* var_ln_g = (const float*)d_in[24];
  const float* var_ln_b = (const float*)d_in[25];
  const float* con_ln_g = (const float*)d_in[26];
  const float* con_ln_b = (const float*)d_in[27];
  float* hv = (float*)d_out;

  char* p = (char*)d_ws;
  auto carve = [&](size_t bytes) { char* r = p; p += (bytes + 255) & ~(size_t)255; return r; };
  int* cnt_c = (int*)carve((size_t)NCN*4);
  int* cur_c = (int*)carve((size_t)NCN*4);
  int* cnt_v = (int*)carve((size_t)NVN*4);
  int* cur_v = (int*)carve((size_t)NVN*4);
  int* off_c = (int*)carve((size_t)(NCN+1)*4);
  int* off_v = (int*)carve((size_t)(NVN+1)*4);
  int* aux   = (int*)carve(1024*4);
  int* lst_c = (int*)carve((size_t)NE*4);
  int* lst_v = (int*)carve((size_t)NE*4);
  float* wf  = (float*)carve((size_t)H*H*4);
  float* bfu = (float*)carve((size_t)H*4);
  unsigned short* wfph = (unsigned short*)carve((size_t)H*H*2);
  unsigned short* wfpl = (unsigned short*)carve((size_t)H*H*2);
  unsigned short* wvph = (unsigned short*)carve((size_t)H*H*2);
  unsigned short* wvpl = (unsigned short*)carve((size_t)H*H*2);
  unsigned short* cgph = (unsigned short*)carve((size_t)2*H*H*2);
  unsigned short* cgpl = (unsigned short*)carve((size_t)2*H*H*2);
  unsigned short* vgph = (unsigned short*)carve((size_t)2*H*H*2);
  unsigned short* vgpl = (unsigned short*)carve((size_t)2*H*H*2);
  float* hc    = (float*)carve((size_t)NCN*H*4);
  float* t_c   = (float*)carve((size_t)NCN*H*4);
  float* t_v   = (float*)carve((size_t)NVN*H*4);
  unsigned short* hvb = (unsigned short*)carve((size_t)NVN*H*2);
  unsigned short* hcb = (unsigned short*)carve((size_t)NCN*H*2);
  if ((size_t)(p - (char*)d_ws) > ws_size) return;

  (void)hipMemsetAsync(cnt_c, 0, (size_t)NCN*4, stream);
  (void)hipMemsetAsync(cur_c, 0, (size_t)NCN*4, stream);
  (void)hipMemsetAsync(cnt_v, 0, (size_t)NVN*4, stream);
  (void)hipMemsetAsync(cur_v, 0, (size_t)NVN*4, stream);

  k_fuse_w<<<64, 256, 0, stream>>>(wmsg, wupd, wf);
  k_fuse_b<<<1, 128, 0, stream>>>(bmsg, wupd, bfu);
  k_perm2<<<(H*H+255)/256, 256, 0, stream>>>(wf, wfph, wfpl, H);
  k_perm2<<<(H*H+255)/256, 256, 0, stream>>>(wc2v, wvph, wvpl, H);
  k_perm2<<<(2*H*H+255)/256, 256, 0, stream>>>(cgate_w, cgph, cgpl, 2*H);
  k_perm2<<<(2*H*H+255)/256, 256, 0, stream>>>(vgate_w, vgph, vgpl, 2*H);

  k_count<<<2048, 256, 0, stream>>>(evc_dst, ecv_dst, cnt_c, cnt_v);
  int nbc = (NCN + 255)/256, nbv = (NVN + 255)/256;
  k_scan1<<<nbc, 256, 0, stream>>>(cnt_c, off_c, aux, NCN);
  k_scan2<<<1, 1024, 0, stream>>>(aux, nbc);
  k_scan3<<<nbc, 256, 0, stream>>>(off_c, aux, NCN, NE);
  k_scan1<<<nbv, 256, 0, stream>>>(cnt_v, off_v, aux, NVN);
  k_scan2<<<1, 1024, 0, stream>>>(aux, nbv);
  k_scan3<<<nbv, 256, 0, stream>>>(off_v, aux, NVN, NE);
  k_scatter<<<2048, 256, 0, stream>>>(evc_src, evc_dst, ecv_src, ecv_dst,
                                      off_c, cur_c, lst_c, off_v, cur_v, lst_v);

  k_init_var<<<NVN/4, 256, 0, stream>>>(x_var, vproj_w, vproj_b, var_ln_g, var_ln_b, hv, hvb);
  k_init_con<<<NCN/4, 256, 0, stream>>>(x_con, cproj_w, cproj_b, con_ln_g, con_ln_b, hc, hcb);

  for (int r = 0; r < 2; ++r) {
    // ---- v2c: gather(hvb)->t_c, then fused mm+LN+gate -> hc/hcb ----
    k_gather_bf<<<(NCN+3)/4, 256, 0, stream>>>((const unsigned int*)hvb, off_c, lst_c, t_c, NCN);
    k_mleg<0><<<(NCN+31)/32, 128, 0, stream>>>(t_c, wfph, wfpl, cnt_c, x_con, bfu, wupd + H*H,
                                               bupd, v2c_ln_g, v2c_ln_b, cgph, cgate_b,
                                               hc, hcb, NCN);
    // ---- c2v: gather(hcb)->t_v, then fused mm+LN+gate -> hv/hvb ----
    k_gather_bf<<<(NVN+3)/4, 256, 0, stream>>>((const unsigned int*)hcb, off_v, lst_v, t_v, NVN);
    k_mleg<1><<<(NVN+31)/32, 128, 0, stream>>>(t_v, wvph, wvpl, cnt_v, nullptr, bc2v, nullptr,
                                               nullptr, c2v_ln_g, c2v_ln_b, vgph, vgate_b,
                                               hv, hvb, NVN);
  }
}

// Round 17
// 622.499 us; speedup vs baseline: 1.0024x; 1.0024x over previous
//
#include <hip/hip_runtime.h>
#include <stdint.h>

#define NVN 100000
#define NCN 50000
#define NE  800000
#define H   128

typedef __attribute__((ext_vector_type(8))) short bf16x8;
typedef __attribute__((ext_vector_type(4))) float f32x4;

static __device__ __forceinline__ float wredsum(float v) {
#pragma unroll
  for (int off = 32; off > 0; off >>= 1) v += __shfl_xor(v, off, 64);
  return v;
}
static __device__ __forceinline__ float sigmoidf(float x) { return 1.0f / (1.0f + __expf(-x)); }
static __device__ __forceinline__ unsigned short f2bf(float f) {
  unsigned int u = __float_as_uint(f);
  return (unsigned short)((u + 0x7FFFu + ((u >> 16) & 1u)) >> 16);  // RNE
}
static __device__ __forceinline__ short2 splitbf(float f) {
  unsigned short h = f2bf(f);
  float hf = __uint_as_float(((unsigned int)h) << 16);
  short2 r;
  r.x = (short)h;
  r.y = (short)f2bf(f - hf);
  return r;
}

// ---------------- init: h = LN(relu(x @ W + b)), writes f32 master + bf16 shadow ----------------
__global__ __launch_bounds__(256) void k_init_var(const float* __restrict__ xv,
    const float* __restrict__ w, const float* __restrict__ b,
    const float* __restrict__ g, const float* __restrict__ bb,
    float* __restrict__ hv, unsigned short* __restrict__ hb) {
  int wid = (blockIdx.x * 256 + threadIdx.x) >> 6;
  int lane = threadIdx.x & 63;
  if (wid >= NVN) return;
  float x0 = xv[wid*4+0], x1 = xv[wid*4+1], x2 = xv[wid*4+2], x3 = xv[wid*4+3];
  int c0 = lane, c1 = lane + 64;
  float v0 = b[c0] + x0*w[c0] + x1*w[H+c0] + x2*w[2*H+c0] + x3*w[3*H+c0];
  float v1 = b[c1] + x0*w[c1] + x1*w[H+c1] + x2*w[2*H+c1] + x3*w[3*H+c1];
  v0 = fmaxf(v0, 0.f); v1 = fmaxf(v1, 0.f);
  float mu = wredsum(v0 + v1) * (1.0f/H);
  float d0 = v0 - mu, d1 = v1 - mu;
  float var = wredsum(d0*d0 + d1*d1) * (1.0f/H);
  float r = rsqrtf(var + 1e-5f);
  float o0 = d0*r*g[c0] + bb[c0], o1 = d1*r*g[c1] + bb[c1];
  hv[(size_t)wid*H + c0] = o0;  hv[(size_t)wid*H + c1] = o1;
  hb[(size_t)wid*H + c0] = f2bf(o0);  hb[(size_t)wid*H + c1] = f2bf(o1);
}

__global__ __launch_bounds__(256) void k_init_con(const float* __restrict__ xc,
    const float* __restrict__ w, const float* __restrict__ b,
    const float* __restrict__ g, const float* __restrict__ bb,
    float* __restrict__ hc, unsigned short* __restrict__ hb) {
  int wid = (blockIdx.x * 256 + threadIdx.x) >> 6;
  int lane = threadIdx.x & 63;
  if (wid >= NCN) return;
  float x = xc[wid];
  int c0 = lane, c1 = lane + 64;
  float v0 = fmaxf(b[c0] + x*w[c0], 0.f);
  float v1 = fmaxf(b[c1] + x*w[c1], 0.f);
  float mu = wredsum(v0 + v1) * (1.0f/H);
  float d0 = v0 - mu, d1 = v1 - mu;
  float var = wredsum(d0*d0 + d1*d1) * (1.0f/H);
  float r = rsqrtf(var + 1e-5f);
  float o0 = d0*r*g[c0] + bb[c0], o1 = d1*r*g[c1] + bb[c1];
  hc[(size_t)wid*H + c0] = o0;  hc[(size_t)wid*H + c1] = o1;
  hb[(size_t)wid*H + c0] = f2bf(o0);  hb[(size_t)wid*H + c1] = f2bf(o1);
}

// ---------------- weight fusion ----------------
__global__ void k_fuse_w(const float* __restrict__ wm, const float* __restrict__ wu,
                         float* __restrict__ wf) {
  int idx = blockIdx.x*256 + threadIdx.x;   // 16384
  int i = idx >> 7, j = idx & 127;
  float a = 0.f;
  for (int k = 0; k < H; ++k) a = fmaf(wm[i*H+k], wu[k*H+j], a);
  wf[idx] = a;
}
__global__ void k_fuse_b(const float* __restrict__ bm, const float* __restrict__ wu,
                         float* __restrict__ bf) {
  int j = threadIdx.x;
  float a = 0.f;
  for (int k = 0; k < H; ++k) a = fmaf(bm[k], wu[k*H+j], a);
  bf[j] = a;
}

// ---------------- weight permutation into MFMA B-fragment order, hi+lo split ----------------
__global__ __launch_bounds__(256) void k_perm2(const float* __restrict__ W,
    unsigned short* __restrict__ Whi, unsigned short* __restrict__ Wlo, int K) {
  int idx = blockIdx.x*256 + threadIdx.x;
  if (idx >= K*H) return;
  int j = idx & 7, lane = (idx >> 3) & 63, ct = (idx >> 9) & 7, kb = idx >> 12;
  int k = kb*32 + (lane >> 4)*8 + j, c = ct*16 + (lane & 15);
  float w = W[k*H + c];
  unsigned short h = f2bf(w);
  float hf = __uint_as_float(((unsigned int)h) << 16);
  Whi[idx] = h;
  Wlo[idx] = f2bf(w - hf);
}

// ---------------- CSR build ----------------
__global__ void k_count(const int* __restrict__ dc, const int* __restrict__ dv,
                        int* __restrict__ cnt_c, int* __restrict__ cnt_v) {
  for (int e = blockIdx.x*blockDim.x + threadIdx.x; e < NE; e += gridDim.x*blockDim.x) {
    atomicAdd(&cnt_c[dc[e]], 1);
    atomicAdd(&cnt_v[dv[e]], 1);
  }
}
// merged c+v block scans: blocks [0,nbc) handle c, [nbc,nbc+nbv) handle v
__global__ __launch_bounds__(256) void k_scan1m(
    const int* __restrict__ in_c, int* __restrict__ out_c, int* __restrict__ aux_c, int nbc, int n_c,
    const int* __restrict__ in_v, int* __restrict__ out_v, int* __restrict__ aux_v, int n_v) {
  const int b = blockIdx.x;
  const int* in; int* out; int* aux; int n; int lb;
  if (b < nbc) { in = in_c; out = out_c; aux = aux_c; n = n_c; lb = b; }
  else         { in = in_v; out = out_v; aux = aux_v; n = n_v; lb = b - nbc; }
  __shared__ int s[256];
  int t = threadIdx.x, i = lb*256 + t;
  int v = (i < n) ? in[i] : 0;
  s[t] = v; __syncthreads();
  for (int off = 1; off < 256; off <<= 1) {
    int x = (t >= off) ? s[t - off] : 0;
    __syncthreads();
    s[t] += x;
    __syncthreads();
  }
  if (i < n) out[i] = s[t] - v;
  if (t == 255) aux[lb] = s[255];
}
__global__ __launch_bounds__(1024) void k_scan2m(int* __restrict__ aux_c, int nbc,
                                                 int* __restrict__ aux_v, int nbv) {
  int* aux = (blockIdx.x == 0) ? aux_c : aux_v;
  int nb   = (blockIdx.x == 0) ? nbc : nbv;
  __shared__ int s[1024];
  int t = threadIdx.x;
  int v = (t < nb) ? aux[t] : 0;
  s[t] = v; __syncthreads();
  for (int off = 1; off < 1024; off <<= 1) {
    int x = (t >= off) ? s[t-off] : 0;
    __syncthreads();
    s[t] += x;
    __syncthreads();
  }
  if (t < nb) aux[t] = s[t] - v;
}
__global__ __launch_bounds__(256) void k_scan3m(
    int* __restrict__ out_c, const int* __restrict__ aux_c, int nbc, int n_c,
    int* __restrict__ out_v, const int* __restrict__ aux_v, int n_v, int total) {
  const int b = blockIdx.x;
  int* out; const int* aux; int n; int lb;
  if (b < nbc) { out = out_c; aux = aux_c; n = n_c; lb = b; }
  else         { out = out_v; aux = aux_v; n = n_v; lb = b - nbc; }
  int i = lb*256 + threadIdx.x;
  if (i < n) out[i] += aux[lb];
  if (i == 0) out[n] = total;
}
// scatter: plain stores (reverted; atomics don't merge lines on CDNA4 — r16 measured).
// cnt used as countdown cursor via atomicSub; bucket fills in reverse (order-free sum downstream).
__global__ void k_scatter(const int* __restrict__ sc, const int* __restrict__ dc,
                          const int* __restrict__ sv, const int* __restrict__ dv,
                          const int* __restrict__ off_c, int* __restrict__ cnt_c, int* __restrict__ lst_c,
                          const int* __restrict__ off_v, int* __restrict__ cnt_v, int* __restrict__ lst_v) {
  for (int e = blockIdx.x*blockDim.x + threadIdx.x; e < NE; e += gridDim.x*blockDim.x) {
    int d = dc[e]; int p = atomicSub(&cnt_c[d], 1) - 1; lst_c[off_c[d] + p] = sc[e];
    d = dv[e];     p = atomicSub(&cnt_v[d], 1) - 1;     lst_v[off_v[d] + p] = sv[e];
  }
}

// ---------------- high-MLP gather: 8 masked slots/chunk, all loads issued before use ----------------
// invalid slots clamp to the bucket's last index -> duplicate row loads are L1 hits (cheap).
__global__ __launch_bounds__(256) void k_gather_bf(const unsigned int* __restrict__ tab,
    const int* __restrict__ off, const int* __restrict__ lst,
    float* __restrict__ out, int n, int tabn) {
  int wid = (blockIdx.x * 256 + threadIdx.x) >> 6;
  int lane = threadIdx.x & 63;
  if (wid >= n) return;
  int s0 = off[wid], s1 = off[wid+1];
  const int grp = lane >> 4, c16 = lane & 15;
  int pl = (s1 - 1 < s0) ? s0 : s1 - 1;      // anchor for masked slots (deg-0 safe)
  if (pl >= NE) pl = NE - 1;
  float acc[8];
#pragma unroll
  for (int j = 0; j < 8; ++j) acc[j] = 0.f;
  for (int base = s0; base < s1; base += 32) {
    int idxs[8];
    float msk[8];
#pragma unroll
    for (int j = 0; j < 8; ++j) {
      int p = base + grp + 4*j;
      msk[j] = (p < s1) ? 1.f : 0.f;
      int pc = (p < s1) ? p : pl;
      int ix = lst[pc];
      ix = ix < 0 ? 0 : (ix >= tabn ? tabn - 1 : ix);
      idxs[j] = ix;
    }
#pragma unroll
    for (int j = 0; j < 8; ++j) {
      uint4 u = *(const uint4*)(tab + (size_t)idxs[j]*64 + c16*4);
      float m = msk[j];
      acc[0] = fmaf(m, __uint_as_float(u.x << 16),          acc[0]);
      acc[1] = fmaf(m, __uint_as_float(u.x & 0xFFFF0000u),  acc[1]);
      acc[2] = fmaf(m, __uint_as_float(u.y << 16),          acc[2]);
      acc[3] = fmaf(m, __uint_as_float(u.y & 0xFFFF0000u),  acc[3]);
      acc[4] = fmaf(m, __uint_as_float(u.z << 16),          acc[4]);
      acc[5] = fmaf(m, __uint_as_float(u.z & 0xFFFF0000u),  acc[5]);
      acc[6] = fmaf(m, __uint_as_float(u.w << 16),          acc[6]);
      acc[7] = fmaf(m, __uint_as_float(u.w & 0xFFFF0000u),  acc[7]);
    }
  }
#pragma unroll
  for (int j = 0; j < 8; ++j) {
    acc[j] += __shfl_xor(acc[j], 16, 64);
    acc[j] += __shfl_xor(acc[j], 32, 64);
  }
  if (lane < 16) {
    float inv = 1.0f / ((float)(s1 - s0) + 1e-6f);
    float* op = out + (size_t)wid*H + c16*8;
    *(float4*)(op)     = make_float4(acc[0]*inv, acc[1]*inv, acc[2]*inv, acc[3]*inv);
    *(float4*)(op + 4) = make_float4(acc[4]*inv, acc[5]*inv, acc[6]*inv, acc[7]*inv);
  }
}

// ====== mega-fused: matmul1 -> LDS park -> SIMT LN -> gate matmul2 -> blend ======
// 2 waves / 128 threads / 32 rows per block; LDS 16.9KB. counts derived from off[].
template<int EPI>
__global__ __launch_bounds__(128) void k_mleg(
    const float* __restrict__ A,
    const unsigned short* __restrict__ Wph, const unsigned short* __restrict__ Wpl,
    const int* __restrict__ off, const float* __restrict__ xc,
    const float* __restrict__ vb, const float* __restrict__ wcl,
    const float* __restrict__ badd, const float* __restrict__ lng,
    const float* __restrict__ lnb,
    const unsigned short* __restrict__ Gph, const float* __restrict__ gb,
    float* __restrict__ Hm, unsigned short* __restrict__ Hb, int n) {
  __shared__ float lds[32][132];               // 16.9KB park buffer
  const int wv = threadIdx.x >> 6, lane = threadIdx.x & 63;
  const int rbase = blockIdx.x*32 + wv*16;
  if (rbase >= n) return;
  const int g = lane >> 4, c15 = lane & 15;
  int arow = rbase + c15; if (arow > n-1) arow = n-1;

  // ---- prefetch A1 = Hm own rows (raw f32), latency hides under matmul1 + LN ----
  const float* Ar1 = Hm + (size_t)arow*H + g*8;
  float4 pf[8];
#pragma unroll
  for (int kb = 0; kb < 4; ++kb) {
    pf[2*kb]   = *(const float4*)(Ar1 + kb*32);
    pf[2*kb+1] = *(const float4*)(Ar1 + kb*32 + 4);
  }

  // ---- matmul1: A @ W (split both operands, 3 MFMA) ----
  {
    const float* Ar = A + (size_t)arow*H + g*8;
    bf16x8 ahi[4], alo[4];
#pragma unroll
    for (int kb = 0; kb < 4; ++kb) {
      float4 p0 = *(const float4*)(Ar + kb*32);
      float4 p1 = *(const float4*)(Ar + kb*32 + 4);
      bf16x8 h, l;
      short2 s;
      s = splitbf(p0.x); h[0] = s.x; l[0] = s.y;
      s = splitbf(p0.y); h[1] = s.x; l[1] = s.y;
      s = splitbf(p0.z); h[2] = s.x; l[2] = s.y;
      s = splitbf(p0.w); h[3] = s.x; l[3] = s.y;
      s = splitbf(p1.x); h[4] = s.x; l[4] = s.y;
      s = splitbf(p1.y); h[5] = s.x; l[5] = s.y;
      s = splitbf(p1.z); h[6] = s.x; l[6] = s.y;
      s = splitbf(p1.w); h[7] = s.x; l[7] = s.y;
      ahi[kb] = h; alo[kb] = l;
    }
    const bf16x8* Bph = (const bf16x8*)Wph;
    const bf16x8* Bpl = (const bf16x8*)Wpl;
    f32x4 zero = {0.f, 0.f, 0.f, 0.f};
    f32x4 acc[8];
#pragma unroll
    for (int ct = 0; ct < 8; ++ct) acc[ct] = zero;
#pragma unroll
    for (int kb = 0; kb < 4; ++kb)
#pragma unroll
      for (int ct = 0; ct < 8; ++ct) {
        bf16x8 bh = Bph[(kb*8+ct)*64 + lane];
        bf16x8 bl = Bpl[(kb*8+ct)*64 + lane];
        acc[ct] = __builtin_amdgcn_mfma_f32_16x16x32_bf16(ahi[kb], bh, acc[ct], 0, 0, 0);
        acc[ct] = __builtin_amdgcn_mfma_f32_16x16x32_bf16(alo[kb], bh, acc[ct], 0, 0, 0);
        acc[ct] = __builtin_amdgcn_mfma_f32_16x16x32_bf16(ahi[kb], bl, acc[ct], 0, 0, 0);
      }
    // park pre-activation into LDS (wave-local rows)
#pragma unroll
    for (int r = 0; r < 4; ++r)
#pragma unroll
      for (int ct = 0; ct < 8; ++ct)
        lds[wv*16 + g*4 + r][ct*16 + c15] = acc[ct][r];
  }

  // ---- proven SIMT LN epilogue; full blocks fully unrolled ----
  {
    float vb0 = vb[lane], vb1 = vb[lane+64];
    float lg0 = lng[lane], lg1 = lng[lane+64];
    float lb0 = lnb[lane], lb1 = lnb[lane+64];
    float wc0 = 0.f, wc1 = 0.f, ba0 = 0.f, ba1 = 0.f;
    if constexpr (EPI == 0) {
      wc0 = wcl[lane]; wc1 = wcl[lane+64];
      ba0 = badd[lane]; ba1 = badd[lane+64];
    }
    auto lnrow = [&](int row, int dst) {
      float cf = (float)(off[dst+1] - off[dst]);
      float scale = cf / (cf + 1e-6f);
      float v0 = lds[row][lane]     + scale*vb0;
      float v1 = lds[row][lane+64]  + scale*vb1;
      if constexpr (EPI == 0) {
        float clue = xc[dst];
        v0 += clue*wc0 + ba0;
        v1 += clue*wc1 + ba1;
      }
      v0 = fmaxf(v0, 0.f); v1 = fmaxf(v1, 0.f);
      float mu = wredsum(v0 + v1) * (1.0f/H);
      float d0 = v0 - mu, d1 = v1 - mu;
      float var = wredsum(d0*d0 + d1*d1) * (1.0f/H);
      float r = rsqrtf(var + 1e-5f);
      lds[row][lane]      = d0*r*lg0 + lb0;
      lds[row][lane + 64] = d1*r*lg1 + lb1;
    };
    const int blk = blockIdx.x*32;
    if (blk + 32 <= n) {
#pragma unroll
      for (int i = 0; i < 16; ++i) lnrow(wv*16 + i, blk + wv*16 + i);
    } else {
      for (int i = 0; i < 16; ++i) {
        int dst = blk + wv*16 + i;
        if (dst >= n) break;
        lnrow(wv*16 + i, dst);
      }
    }
  }

  // ---- matmul2: [Hm(prefetched) | c_new(LDS)] @ G (A split, B hi-only) + sigmoid gate ----
  {
    bf16x8 ahi[8], alo[8];
#pragma unroll
    for (int kb = 0; kb < 4; ++kb) {
      float4 p0 = pf[2*kb];
      float4 p1 = pf[2*kb+1];
      bf16x8 h, l;
      short2 s;
      s = splitbf(p0.x); h[0] = s.x; l[0] = s.y;
      s = splitbf(p0.y); h[1] = s.x; l[1] = s.y;
      s = splitbf(p0.z); h[2] = s.x; l[2] = s.y;
      s = splitbf(p0.w); h[3] = s.x; l[3] = s.y;
      s = splitbf(p1.x); h[4] = s.x; l[4] = s.y;
      s = splitbf(p1.y); h[5] = s.x; l[5] = s.y;
      s = splitbf(p1.z); h[6] = s.x; l[6] = s.y;
      s = splitbf(p1.w); h[7] = s.x; l[7] = s.y;
      ahi[kb] = h; alo[kb] = l;
    }
    const float* Ar2 = &lds[wv*16 + c15][0];               // c_new (LDS, own wave rows)
#pragma unroll
    for (int kb = 4; kb < 8; ++kb) {
      float4 p0 = *(const float4*)(Ar2 + (kb-4)*32 + g*8);
      float4 p1 = *(const float4*)(Ar2 + (kb-4)*32 + g*8 + 4);
      bf16x8 h, l;
      short2 s;
      s = splitbf(p0.x); h[0] = s.x; l[0] = s.y;
      s = splitbf(p0.y); h[1] = s.x; l[1] = s.y;
      s = splitbf(p0.z); h[2] = s.x; l[2] = s.y;
      s = splitbf(p0.w); h[3] = s.x; l[3] = s.y;
      s = splitbf(p1.x); h[4] = s.x; l[4] = s.y;
      s = splitbf(p1.y); h[5] = s.x; l[5] = s.y;
      s = splitbf(p1.z); h[6] = s.x; l[6] = s.y;
      s = splitbf(p1.w); h[7] = s.x; l[7] = s.y;
      ahi[kb] = h; alo[kb] = l;
    }
    const bf16x8* Bph = (const bf16x8*)Gph;
    f32x4 zero = {0.f, 0.f, 0.f, 0.f};
    f32x4 acc[8];
#pragma unroll
    for (int ct = 0; ct < 8; ++ct) acc[ct] = zero;
#pragma unroll
    for (int kb = 0; kb < 8; ++kb)
#pragma unroll
      for (int ct = 0; ct < 8; ++ct) {
        bf16x8 bh = Bph[(kb*8+ct)*64 + lane];
        acc[ct] = __builtin_amdgcn_mfma_f32_16x16x32_bf16(ahi[kb], bh, acc[ct], 0, 0, 0);
        acc[ct] = __builtin_amdgcn_mfma_f32_16x16x32_bf16(alo[kb], bh, acc[ct], 0, 0, 0);
      }
    float gbv[8];
#pragma unroll
    for (int ct = 0; ct < 8; ++ct) gbv[ct] = gb[ct*16 + c15];
#pragma unroll
    for (int r = 0; r < 4; ++r) {
      int rg = rbase + g*4 + r;
      if (rg >= n) continue;
      int row = wv*16 + g*4 + r;
      float* hp = Hm + (size_t)rg*H + c15;
      unsigned short* hbp = Hb + (size_t)rg*H + c15;
#pragma unroll
      for (int ct = 0; ct < 8; ++ct) {
        float gg = sigmoidf(acc[ct][r] + gbv[ct]);
        float nv = lds[row][ct*16 + c15];
        float ov = hp[ct*16];
        float res = gg*nv + (1.f - gg)*ov;
        hp[ct*16] = res;
        hbp[ct*16] = f2bf(res);
      }
    }
  }
}

extern "C" void kernel_launch(void* const* d_in, const int* in_sizes, int n_in,
                              void* d_out, int out_size, void* d_ws, size_t ws_size,
                              hipStream_t stream) {
  const float* x_var   = (const float*)d_in[0];
  const float* x_con   = (const float*)d_in[1];
  const int*   evc_src = (const int*)d_in[2];
  const int*   evc_dst = (const int*)d_in[3];
  const int*   ecv_src = (const int*)d_in[4];
  const int*   ecv_dst = (const int*)d_in[5];
  const float* vproj_w = (const float*)d_in[6];
  const float* vproj_b = (const float*)d_in[7];
  const float* cproj_w = (const float*)d_in[8];
  const float* cproj_b = (const float*)d_in[9];
  const float* wmsg    = (const float*)d_in[10];
  const float* bmsg    = (const float*)d_in[11];
  const float* wupd    = (const float*)d_in[12];
  const float* bupd    = (const float*)d_in[13];
  const float* v2c_ln_g = (const float*)d_in[14];
  const float* v2c_ln_b = (const float*)d_in[15];
  const float* wc2v    = (const float*)d_in[16];
  const float* bc2v    = (const float*)d_in[17];
  const float* c2v_ln_g = (const float*)d_in[18];
  const float* c2v_ln_b = (const float*)d_in[19];
  const float* vgate_w = (const float*)d_in[20];
  const float* vgate_b = (const float*)d_in[21];
  const float* cgate_w = (const float*)d_in[22];
  const float* cgate_b = (const float*)d_in[23];
  const float* var_ln_g = (const float*)d_in[24];
  const float* var_ln_b = (const float*)d_in[25];
  const float* con_ln_g = (const float*)d_in[26];
  const float* con_ln_b = (const float*)d_in[27];
  float* hv = (float*)d_out;

  char* p = (char*)d_ws;
  auto carve = [&](size_t bytes) { char* r = p; p += (bytes + 255) & ~(size_t)255; return r; };
  int* cnt_c = (int*)carve((size_t)NCN*4);
  int* cnt_v = (int*)carve((size_t)NVN*4);
  int* off_c = (int*)carve((size_t)(NCN+1)*4);
  int* off_v = (int*)carve((size_t)(NVN+1)*4);
  int* aux_c = (int*)carve(1024*4);
  int* aux_v = (int*)carve(1024*4);
  int* lst_c = (int*)carve((size_t)NE*4);
  int* lst_v = (int*)carve((size_t)NE*4);
  float* wf  = (float*)carve((size_t)H*H*4);
  float* bfu = (float*)carve((size_t)H*4);
  unsigned short* wfph = (unsigned short*)carve((size_t)H*H*2);
  unsigned short* wfpl = (unsigned short*)carve((size_t)H*H*2);
  unsigned short* wvph = (unsigned short*)carve((size_t)H*H*2);
  unsigned short* wvpl = (unsigned short*)carve((size_t)H*H*2);
  unsigned short* cgph = (unsigned short*)carve((size_t)2*H*H*2);
  unsigned short* cgpl = (unsigned short*)carve((size_t)2*H*H*2);
  unsigned short* vgph = (unsigned short*)carve((size_t)2*H*H*2);
  unsigned short* vgpl = (unsigned short*)carve((size_t)2*H*H*2);
  float* hc    = (float*)carve((size_t)NCN*H*4);
  float* t_c   = (float*)carve((size_t)NCN*H*4);
  float* t_v   = (float*)carve((size_t)NVN*H*4);
  unsigned short* hvb = (unsigned short*)carve((size_t)NVN*H*2);
  unsigned short* hcb = (unsigned short*)carve((size_t)NCN*H*2);
  if ((size_t)(p - (char*)d_ws) > ws_size) return;

  (void)hipMemsetAsync(cnt_c, 0, (size_t)NCN*4, stream);
  (void)hipMemsetAsync(cnt_v, 0, (size_t)NVN*4, stream);

  k_fuse_w<<<64, 256, 0, stream>>>(wmsg, wupd, wf);
  k_fuse_b<<<1, 128, 0, stream>>>(bmsg, wupd, bfu);
  k_perm2<<<(H*H+255)/256, 256, 0, stream>>>(wf, wfph, wfpl, H);
  k_perm2<<<(H*H+255)/256, 256, 0, stream>>>(wc2v, wvph, wvpl, H);
  k_perm2<<<(2*H*H+255)/256, 256, 0, stream>>>(cgate_w, cgph, cgpl, 2*H);
  k_perm2<<<(2*H*H+255)/256, 256, 0, stream>>>(vgate_w, vgph, vgpl, 2*H);

  k_count<<<2048, 256, 0, stream>>>(evc_dst, ecv_dst, cnt_c, cnt_v);
  int nbc = (NCN + 255)/256, nbv = (NVN + 255)/256;
  k_scan1m<<<nbc + nbv, 256, 0, stream>>>(cnt_c, off_c, aux_c, nbc, NCN,
                                          cnt_v, off_v, aux_v, NVN);
  k_scan2m<<<2, 1024, 0, stream>>>(aux_c, nbc, aux_v, nbv);
  k_scan3m<<<nbc + nbv, 256, 0, stream>>>(off_c, aux_c, nbc, NCN,
                                          off_v, aux_v, NVN, NE);
  k_scatter<<<2048, 256, 0, stream>>>(evc_src, evc_dst, ecv_src, ecv_dst,
                                      off_c, cnt_c, lst_c, off_v, cnt_v, lst_v);

  k_init_var<<<NVN/4, 256, 0, stream>>>(x_var, vproj_w, vproj_b, var_ln_g, var_ln_b, hv, hvb);
  k_init_con<<<NCN/4, 256, 0, stream>>>(x_con, cproj_w, cproj_b, con_ln_g, con_ln_b, hc, hcb);

  for (int r = 0; r < 2; ++r) {
    // ---- v2c: gather(hvb)->t_c, then fused mm+LN+gate -> hc/hcb ----
    k_gather_bf<<<(NCN+3)/4, 256, 0, stream>>>((const unsigned int*)hvb, off_c, lst_c,
                                               t_c, NCN, NVN);
    k_mleg<0><<<(NCN+31)/32, 128, 0, stream>>>(t_c, wfph, wfpl, off_c, x_con, bfu, wupd + H*H,
                                               bupd, v2c_ln_g, v2c_ln_b, cgph, cgate_b,
                                               hc, hcb, NCN);
    // ---- c2v: gather(hcb)->t_v, then fused mm+LN+gate -> hv/hvb ----
    k_gather_bf<<<(NVN+3)/4, 256, 0, stream>>>((const unsigned int*)hcb, off_v, lst_v,
                                               t_v, NVN, NCN);
    k_mleg<1><<<(NVN+31)/32, 128, 0, stream>>>(t_v, wvph, wvpl, off_v, nullptr, bc2v, nullptr,
                                               nullptr, c2v_ln_g, c2v_ln_b, vgph, vgate_b,
                                               hv, hvb, NVN);
  }
}

// Round 18
// 588.560 us; speedup vs baseline: 1.0602x; 1.0577x over previous
//
#include <hip/hip_runtime.h>
#include <stdint.h>

#define NVN 100000
#define NCN 50000
#define NE  800000
#define H   128

typedef __attribute__((ext_vector_type(8))) short bf16x8;
typedef __attribute__((ext_vector_type(4))) float f32x4;

static __device__ __forceinline__ float wredsum(float v) {
#pragma unroll
  for (int off = 32; off > 0; off >>= 1) v += __shfl_xor(v, off, 64);
  return v;
}
static __device__ __forceinline__ float sigmoidf(float x) { return 1.0f / (1.0f + __expf(-x)); }
static __device__ __forceinline__ unsigned short f2bf(float f) {
  unsigned int u = __float_as_uint(f);
  return (unsigned short)((u + 0x7FFFu + ((u >> 16) & 1u)) >> 16);  // RNE
}
static __device__ __forceinline__ short2 splitbf(float f) {
  unsigned short h = f2bf(f);
  float hf = __uint_as_float(((unsigned int)h) << 16);
  short2 r;
  r.x = (short)h;
  r.y = (short)f2bf(f - hf);
  return r;
}

// ---------------- init: h = LN(relu(x @ W + b)), writes f32 master + bf16 shadow ----------------
__global__ __launch_bounds__(256) void k_init_var(const float* __restrict__ xv,
    const float* __restrict__ w, const float* __restrict__ b,
    const float* __restrict__ g, const float* __restrict__ bb,
    float* __restrict__ hv, unsigned short* __restrict__ hb) {
  int wid = (blockIdx.x * 256 + threadIdx.x) >> 6;
  int lane = threadIdx.x & 63;
  if (wid >= NVN) return;
  float x0 = xv[wid*4+0], x1 = xv[wid*4+1], x2 = xv[wid*4+2], x3 = xv[wid*4+3];
  int c0 = lane, c1 = lane + 64;
  float v0 = b[c0] + x0*w[c0] + x1*w[H+c0] + x2*w[2*H+c0] + x3*w[3*H+c0];
  float v1 = b[c1] + x0*w[c1] + x1*w[H+c1] + x2*w[2*H+c1] + x3*w[3*H+c1];
  v0 = fmaxf(v0, 0.f); v1 = fmaxf(v1, 0.f);
  float mu = wredsum(v0 + v1) * (1.0f/H);
  float d0 = v0 - mu, d1 = v1 - mu;
  float var = wredsum(d0*d0 + d1*d1) * (1.0f/H);
  float r = rsqrtf(var + 1e-5f);
  float o0 = d0*r*g[c0] + bb[c0], o1 = d1*r*g[c1] + bb[c1];
  hv[(size_t)wid*H + c0] = o0;  hv[(size_t)wid*H + c1] = o1;
  hb[(size_t)wid*H + c0] = f2bf(o0);  hb[(size_t)wid*H + c1] = f2bf(o1);
}

__global__ __launch_bounds__(256) void k_init_con(const float* __restrict__ xc,
    const float* __restrict__ w, const float* __restrict__ b,
    const float* __restrict__ g, const float* __restrict__ bb,
    float* __restrict__ hc, unsigned short* __restrict__ hb) {
  int wid = (blockIdx.x * 256 + threadIdx.x) >> 6;
  int lane = threadIdx.x & 63;
  if (wid >= NCN) return;
  float x = xc[wid];
  int c0 = lane, c1 = lane + 64;
  float v0 = fmaxf(b[c0] + x*w[c0], 0.f);
  float v1 = fmaxf(b[c1] + x*w[c1], 0.f);
  float mu = wredsum(v0 + v1) * (1.0f/H);
  float d0 = v0 - mu, d1 = v1 - mu;
  float var = wredsum(d0*d0 + d1*d1) * (1.0f/H);
  float r = rsqrtf(var + 1e-5f);
  float o0 = d0*r*g[c0] + bb[c0], o1 = d1*r*g[c1] + bb[c1];
  hc[(size_t)wid*H + c0] = o0;  hc[(size_t)wid*H + c1] = o1;
  hb[(size_t)wid*H + c0] = f2bf(o0);  hb[(size_t)wid*H + c1] = f2bf(o1);
}

// ---------------- weight fusion ----------------
__global__ void k_fuse_w(const float* __restrict__ wm, const float* __restrict__ wu,
                         float* __restrict__ wf) {
  int idx = blockIdx.x*256 + threadIdx.x;   // 16384
  int i = idx >> 7, j = idx & 127;
  float a = 0.f;
  for (int k = 0; k < H; ++k) a = fmaf(wm[i*H+k], wu[k*H+j], a);
  wf[idx] = a;
}
__global__ void k_fuse_b(const float* __restrict__ bm, const float* __restrict__ wu,
                         float* __restrict__ bf) {
  int j = threadIdx.x;
  float a = 0.f;
  for (int k = 0; k < H; ++k) a = fmaf(bm[k], wu[k*H+j], a);
  bf[j] = a;
}

// ---------------- weight permutation into MFMA B-fragment order, hi+lo split ----------------
__global__ __launch_bounds__(256) void k_perm2(const float* __restrict__ W,
    unsigned short* __restrict__ Whi, unsigned short* __restrict__ Wlo, int K) {
  int idx = blockIdx.x*256 + threadIdx.x;
  if (idx >= K*H) return;
  int j = idx & 7, lane = (idx >> 3) & 63, ct = (idx >> 9) & 7, kb = idx >> 12;
  int k = kb*32 + (lane >> 4)*8 + j, c = ct*16 + (lane & 15);
  float w = W[k*H + c];
  unsigned short h = f2bf(w);
  float hf = __uint_as_float(((unsigned int)h) << 16);
  Whi[idx] = h;
  Wlo[idx] = f2bf(w - hf);
}

// ---------------- CSR build ----------------
__global__ void k_count(const int* __restrict__ dc, const int* __restrict__ dv,
                        int* __restrict__ cnt_c, int* __restrict__ cnt_v) {
  for (int e = blockIdx.x*blockDim.x + threadIdx.x; e < NE; e += gridDim.x*blockDim.x) {
    atomicAdd(&cnt_c[dc[e]], 1);
    atomicAdd(&cnt_v[dv[e]], 1);
  }
}
// merged c+v block scans: blocks [0,nbc) handle c, [nbc,nbc+nbv) handle v
__global__ __launch_bounds__(256) void k_scan1m(
    const int* __restrict__ in_c, int* __restrict__ out_c, int* __restrict__ aux_c, int nbc, int n_c,
    const int* __restrict__ in_v, int* __restrict__ out_v, int* __restrict__ aux_v, int n_v) {
  const int b = blockIdx.x;
  const int* in; int* out; int* aux; int n; int lb;
  if (b < nbc) { in = in_c; out = out_c; aux = aux_c; n = n_c; lb = b; }
  else         { in = in_v; out = out_v; aux = aux_v; n = n_v; lb = b - nbc; }
  __shared__ int s[256];
  int t = threadIdx.x, i = lb*256 + t;
  int v = (i < n) ? in[i] : 0;
  s[t] = v; __syncthreads();
  for (int off = 1; off < 256; off <<= 1) {
    int x = (t >= off) ? s[t - off] : 0;
    __syncthreads();
    s[t] += x;
    __syncthreads();
  }
  if (i < n) out[i] = s[t] - v;
  if (t == 255) aux[lb] = s[255];
}
__global__ __launch_bounds__(1024) void k_scan2m(int* __restrict__ aux_c, int nbc,
                                                 int* __restrict__ aux_v, int nbv) {
  int* aux = (blockIdx.x == 0) ? aux_c : aux_v;
  int nb   = (blockIdx.x == 0) ? nbc : nbv;
  __shared__ int s[1024];
  int t = threadIdx.x;
  int v = (t < nb) ? aux[t] : 0;
  s[t] = v; __syncthreads();
  for (int off = 1; off < 1024; off <<= 1) {
    int x = (t >= off) ? s[t-off] : 0;
    __syncthreads();
    s[t] += x;
    __syncthreads();
  }
  if (t < nb) aux[t] = s[t] - v;
}
__global__ __launch_bounds__(256) void k_scan3m(
    int* __restrict__ out_c, const int* __restrict__ aux_c, int nbc, int n_c,
    int* __restrict__ out_v, const int* __restrict__ aux_v, int n_v, int total) {
  const int b = blockIdx.x;
  int* out; const int* aux; int n; int lb;
  if (b < nbc) { out = out_c; aux = aux_c; n = n_c; lb = b; }
  else         { out = out_v; aux = aux_v; n = n_v; lb = b - nbc; }
  int i = lb*256 + threadIdx.x;
  if (i < n) out[i] += aux[lb];
  if (i == 0) out[n] = total;
}
// scatter (r15-proven): forward cursor + plain stores
__global__ void k_scatter(const int* __restrict__ sc, const int* __restrict__ dc,
                          const int* __restrict__ sv, const int* __restrict__ dv,
                          const int* __restrict__ off_c, int* __restrict__ cur_c, int* __restrict__ lst_c,
                          const int* __restrict__ off_v, int* __restrict__ cur_v, int* __restrict__ lst_v) {
  for (int e = blockIdx.x*blockDim.x + threadIdx.x; e < NE; e += gridDim.x*blockDim.x) {
    int d = dc[e]; int p = atomicAdd(&cur_c[d], 1); lst_c[off_c[d] + p] = sc[e];
    d = dv[e];     p = atomicAdd(&cur_v[d], 1);     lst_v[off_v[d] + p] = sv[e];
  }
}

// ---------------- lane-packed gather (r15-proven): 16 lanes/row-octet x 4 edge slots ----------------
__global__ __launch_bounds__(256) void k_gather_bf(const unsigned int* __restrict__ tab,
    const int* __restrict__ off, const int* __restrict__ lst,
    float* __restrict__ out, int n) {
  int wid = (blockIdx.x * 256 + threadIdx.x) >> 6;
  int lane = threadIdx.x & 63;
  if (wid >= n) return;
  int s0 = off[wid], s1 = off[wid+1];
  const int grp = lane >> 4, c16 = lane & 15;
  float acc[8];
#pragma unroll
  for (int j = 0; j < 8; ++j) acc[j] = 0.f;
#pragma unroll 2
  for (int p = s0 + grp; p < s1; p += 4) {
    int idx = lst[p];
    uint4 u = *(const uint4*)(tab + (size_t)idx*64 + c16*4);
    acc[0] += __uint_as_float(u.x << 16);
    acc[1] += __uint_as_float(u.x & 0xFFFF0000u);
    acc[2] += __uint_as_float(u.y << 16);
    acc[3] += __uint_as_float(u.y & 0xFFFF0000u);
    acc[4] += __uint_as_float(u.z << 16);
    acc[5] += __uint_as_float(u.z & 0xFFFF0000u);
    acc[6] += __uint_as_float(u.w << 16);
    acc[7] += __uint_as_float(u.w & 0xFFFF0000u);
  }
#pragma unroll
  for (int j = 0; j < 8; ++j) {
    acc[j] += __shfl_xor(acc[j], 16, 64);
    acc[j] += __shfl_xor(acc[j], 32, 64);
  }
  if (lane < 16) {
    float inv = 1.0f / ((float)(s1 - s0) + 1e-6f);
    float* op = out + (size_t)wid*H + c16*8;
    *(float4*)(op)     = make_float4(acc[0]*inv, acc[1]*inv, acc[2]*inv, acc[3]*inv);
    *(float4*)(op + 4) = make_float4(acc[4]*inv, acc[5]*inv, acc[6]*inv, acc[7]*inv);
  }
}

// ====== mega-fused: matmul1 -> LDS park -> SIMT LN -> gate matmul2 -> blend ======
// 2 waves / 128 threads / 32 rows per block; LDS 16.9KB. counts derived from off[].
template<int EPI>
__global__ __launch_bounds__(128) void k_mleg(
    const float* __restrict__ A,
    const unsigned short* __restrict__ Wph, const unsigned short* __restrict__ Wpl,
    const int* __restrict__ off, const float* __restrict__ xc,
    const float* __restrict__ vb, const float* __restrict__ wcl,
    const float* __restrict__ badd, const float* __restrict__ lng,
    const float* __restrict__ lnb,
    const unsigned short* __restrict__ Gph, const float* __restrict__ gb,
    float* __restrict__ Hm, unsigned short* __restrict__ Hb, int n) {
  __shared__ float lds[32][132];               // 16.9KB park buffer
  const int wv = threadIdx.x >> 6, lane = threadIdx.x & 63;
  const int rbase = blockIdx.x*32 + wv*16;
  if (rbase >= n) return;
  const int g = lane >> 4, c15 = lane & 15;
  int arow = rbase + c15; if (arow > n-1) arow = n-1;

  // ---- prefetch A1 = Hm own rows (raw f32), latency hides under matmul1 + LN ----
  const float* Ar1 = Hm + (size_t)arow*H + g*8;
  float4 pf[8];
#pragma unroll
  for (int kb = 0; kb < 4; ++kb) {
    pf[2*kb]   = *(const float4*)(Ar1 + kb*32);
    pf[2*kb+1] = *(const float4*)(Ar1 + kb*32 + 4);
  }

  // ---- matmul1: A @ W (split both operands, 3 MFMA) ----
  {
    const float* Ar = A + (size_t)arow*H + g*8;
    bf16x8 ahi[4], alo[4];
#pragma unroll
    for (int kb = 0; kb < 4; ++kb) {
      float4 p0 = *(const float4*)(Ar + kb*32);
      float4 p1 = *(const float4*)(Ar + kb*32 + 4);
      bf16x8 h, l;
      short2 s;
      s = splitbf(p0.x); h[0] = s.x; l[0] = s.y;
      s = splitbf(p0.y); h[1] = s.x; l[1] = s.y;
      s = splitbf(p0.z); h[2] = s.x; l[2] = s.y;
      s = splitbf(p0.w); h[3] = s.x; l[3] = s.y;
      s = splitbf(p1.x); h[4] = s.x; l[4] = s.y;
      s = splitbf(p1.y); h[5] = s.x; l[5] = s.y;
      s = splitbf(p1.z); h[6] = s.x; l[6] = s.y;
      s = splitbf(p1.w); h[7] = s.x; l[7] = s.y;
      ahi[kb] = h; alo[kb] = l;
    }
    const bf16x8* Bph = (const bf16x8*)Wph;
    const bf16x8* Bpl = (const bf16x8*)Wpl;
    f32x4 zero = {0.f, 0.f, 0.f, 0.f};
    f32x4 acc[8];
#pragma unroll
    for (int ct = 0; ct < 8; ++ct) acc[ct] = zero;
#pragma unroll
    for (int kb = 0; kb < 4; ++kb)
#pragma unroll
      for (int ct = 0; ct < 8; ++ct) {
        bf16x8 bh = Bph[(kb*8+ct)*64 + lane];
        bf16x8 bl = Bpl[(kb*8+ct)*64 + lane];
        acc[ct] = __builtin_amdgcn_mfma_f32_16x16x32_bf16(ahi[kb], bh, acc[ct], 0, 0, 0);
        acc[ct] = __builtin_amdgcn_mfma_f32_16x16x32_bf16(alo[kb], bh, acc[ct], 0, 0, 0);
        acc[ct] = __builtin_amdgcn_mfma_f32_16x16x32_bf16(ahi[kb], bl, acc[ct], 0, 0, 0);
      }
    // park pre-activation into LDS (wave-local rows)
#pragma unroll
    for (int r = 0; r < 4; ++r)
#pragma unroll
      for (int ct = 0; ct < 8; ++ct)
        lds[wv*16 + g*4 + r][ct*16 + c15] = acc[ct][r];
  }

  // ---- proven SIMT LN epilogue; full blocks fully unrolled ----
  {
    float vb0 = vb[lane], vb1 = vb[lane+64];
    float lg0 = lng[lane], lg1 = lng[lane+64];
    float lb0 = lnb[lane], lb1 = lnb[lane+64];
    float wc0 = 0.f, wc1 = 0.f, ba0 = 0.f, ba1 = 0.f;
    if constexpr (EPI == 0) {
      wc0 = wcl[lane]; wc1 = wcl[lane+64];
      ba0 = badd[lane]; ba1 = badd[lane+64];
    }
    auto lnrow = [&](int row, int dst) {
      float cf = (float)(off[dst+1] - off[dst]);
      float scale = cf / (cf + 1e-6f);
      float v0 = lds[row][lane]     + scale*vb0;
      float v1 = lds[row][lane+64]  + scale*vb1;
      if constexpr (EPI == 0) {
        float clue = xc[dst];
        v0 += clue*wc0 + ba0;
        v1 += clue*wc1 + ba1;
      }
      v0 = fmaxf(v0, 0.f); v1 = fmaxf(v1, 0.f);
      float mu = wredsum(v0 + v1) * (1.0f/H);
      float d0 = v0 - mu, d1 = v1 - mu;
      float var = wredsum(d0*d0 + d1*d1) * (1.0f/H);
      float r = rsqrtf(var + 1e-5f);
      lds[row][lane]      = d0*r*lg0 + lb0;
      lds[row][lane + 64] = d1*r*lg1 + lb1;
    };
    const int blk = blockIdx.x*32;
    if (blk + 32 <= n) {
#pragma unroll
      for (int i = 0; i < 16; ++i) lnrow(wv*16 + i, blk + wv*16 + i);
    } else {
      for (int i = 0; i < 16; ++i) {
        int dst = blk + wv*16 + i;
        if (dst >= n) break;
        lnrow(wv*16 + i, dst);
      }
    }
  }

  // ---- matmul2: [Hm(prefetched) | c_new(LDS)] @ G (A split, B hi-only) + sigmoid gate ----
  {
    bf16x8 ahi[8], alo[8];
#pragma unroll
    for (int kb = 0; kb < 4; ++kb) {
      float4 p0 = pf[2*kb];
      float4 p1 = pf[2*kb+1];
      bf16x8 h, l;
      short2 s;
      s = splitbf(p0.x); h[0] = s.x; l[0] = s.y;
      s = splitbf(p0.y); h[1] = s.x; l[1] = s.y;
      s = splitbf(p0.z); h[2] = s.x; l[2] = s.y;
      s = splitbf(p0.w); h[3] = s.x; l[3] = s.y;
      s = splitbf(p1.x); h[4] = s.x; l[4] = s.y;
      s = splitbf(p1.y); h[5] = s.x; l[5] = s.y;
      s = splitbf(p1.z); h[6] = s.x; l[6] = s.y;
      s = splitbf(p1.w); h[7] = s.x; l[7] = s.y;
      ahi[kb] = h; alo[kb] = l;
    }
    const float* Ar2 = &lds[wv*16 + c15][0];               // c_new (LDS, own wave rows)
#pragma unroll
    for (int kb = 4; kb < 8; ++kb) {
      float4 p0 = *(const float4*)(Ar2 + (kb-4)*32 + g*8);
      float4 p1 = *(const float4*)(Ar2 + (kb-4)*32 + g*8 + 4);
      bf16x8 h, l;
      short2 s;
      s = splitbf(p0.x); h[0] = s.x; l[0] = s.y;
      s = splitbf(p0.y); h[1] = s.x; l[1] = s.y;
      s = splitbf(p0.z); h[2] = s.x; l[2] = s.y;
      s = splitbf(p0.w); h[3] = s.x; l[3] = s.y;
      s = splitbf(p1.x); h[4] = s.x; l[4] = s.y;
      s = splitbf(p1.y); h[5] = s.x; l[5] = s.y;
      s = splitbf(p1.z); h[6] = s.x; l[6] = s.y;
      s = splitbf(p1.w); h[7] = s.x; l[7] = s.y;
      ahi[kb] = h; alo[kb] = l;
    }
    const bf16x8* Bph = (const bf16x8*)Gph;
    f32x4 zero = {0.f, 0.f, 0.f, 0.f};
    f32x4 acc[8];
#pragma unroll
    for (int ct = 0; ct < 8; ++ct) acc[ct] = zero;
#pragma unroll
    for (int kb = 0; kb < 8; ++kb)
#pragma unroll
      for (int ct = 0; ct < 8; ++ct) {
        bf16x8 bh = Bph[(kb*8+ct)*64 + lane];
        acc[ct] = __builtin_amdgcn_mfma_f32_16x16x32_bf16(ahi[kb], bh, acc[ct], 0, 0, 0);
        acc[ct] = __builtin_amdgcn_mfma_f32_16x16x32_bf16(alo[kb], bh, acc[ct], 0, 0, 0);
      }
    float gbv[8];
#pragma unroll
    for (int ct = 0; ct < 8; ++ct) gbv[ct] = gb[ct*16 + c15];
#pragma unroll
    for (int r = 0; r < 4; ++r) {
      int rg = rbase + g*4 + r;
      if (rg >= n) continue;
      int row = wv*16 + g*4 + r;
      float* hp = Hm + (size_t)rg*H + c15;
      unsigned short* hbp = Hb + (size_t)rg*H + c15;
#pragma unroll
      for (int ct = 0; ct < 8; ++ct) {
        float gg = sigmoidf(acc[ct][r] + gbv[ct]);
        float nv = lds[row][ct*16 + c15];
        float ov = hp[ct*16];
        float res = gg*nv + (1.f - gg)*ov;
        hp[ct*16] = res;
        hbp[ct*16] = f2bf(res);
      }
    }
  }
}

extern "C" void kernel_launch(void* const* d_in, const int* in_sizes, int n_in,
                              void* d_out, int out_size, void* d_ws, size_t ws_size,
                              hipStream_t stream) {
  const float* x_var   = (const float*)d_in[0];
  const float* x_con   = (const float*)d_in[1];
  const int*   evc_src = (const int*)d_in[2];
  const int*   evc_dst = (const int*)d_in[3];
  const int*   ecv_src = (const int*)d_in[4];
  const int*   ecv_dst = (const int*)d_in[5];
  const float* vproj_w = (const float*)d_in[6];
  const float* vproj_b = (const float*)d_in[7];
  const float* cproj_w = (const float*)d_in[8];
  const float* cproj_b = (const float*)d_in[9];
  const float* wmsg    = (const float*)d_in[10];
  const float* bmsg    = (const float*)d_in[11];
  const float* wupd    = (const float*)d_in[12];
  const float* bupd    = (const float*)d_in[13];
  const float* v2c_ln_g = (const float*)d_in[14];
  const float* v2c_ln_b = (const float*)d_in[15];
  const float* wc2v    = (const float*)d_in[16];
  const float* bc2v    = (const float*)d_in[17];
  const float* c2v_ln_g = (const float*)d_in[18];
  const float* c2v_ln_b = (const float*)d_in[19];
  const float* vgate_w = (const float*)d_in[20];
  const float* vgate_b = (const float*)d_in[21];
  const float* cgate_w = (const float*)d_in[22];
  const float* cgate_b = (const float*)d_in[23];
  const float* var_ln_g = (const float*)d_in[24];
  const float* var_ln_b = (const float*)d_in[25];
  const float* con_ln_g = (const float*)d_in[26];
  const float* con_ln_b = (const float*)d_in[27];
  float* hv = (float*)d_out;

  char* p = (char*)d_ws;
  auto carve = [&](size_t bytes) { char* r = p; p += (bytes + 255) & ~(size_t)255; return r; };
  int* cnt_c = (int*)carve((size_t)NCN*4);
  int* cur_c = (int*)carve((size_t)NCN*4);
  int* cnt_v = (int*)carve((size_t)NVN*4);
  int* cur_v = (int*)carve((size_t)NVN*4);
  int* off_c = (int*)carve((size_t)(NCN+1)*4);
  int* off_v = (int*)carve((size_t)(NVN+1)*4);
  int* aux_c = (int*)carve(1024*4);
  int* aux_v = (int*)carve(1024*4);
  int* lst_c = (int*)carve((size_t)NE*4);
  int* lst_v = (int*)carve((size_t)NE*4);
  float* wf  = (float*)carve((size_t)H*H*4);
  float* bfu = (float*)carve((size_t)H*4);
  unsigned short* wfph = (unsigned short*)carve((size_t)H*H*2);
  unsigned short* wfpl = (unsigned short*)carve((size_t)H*H*2);
  unsigned short* wvph = (unsigned short*)carve((size_t)H*H*2);
  unsigned short* wvpl = (unsigned short*)carve((size_t)H*H*2);
  unsigned short* cgph = (unsigned short*)carve((size_t)2*H*H*2);
  unsigned short* cgpl = (unsigned short*)carve((size_t)2*H*H*2);
  unsigned short* vgph = (unsigned short*)carve((size_t)2*H*H*2);
  unsigned short* vgpl = (unsigned short*)carve((size_t)2*H*H*2);
  float* hc    = (float*)carve((size_t)NCN*H*4);
  float* t_c   = (float*)carve((size_t)NCN*H*4);
  float* t_v   = (float*)carve((size_t)NVN*H*4);
  unsigned short* hvb = (unsigned short*)carve((size_t)NVN*H*2);
  unsigned short* hcb = (unsigned short*)carve((size_t)NCN*H*2);
  if ((size_t)(p - (char*)d_ws) > ws_size) return;

  (void)hipMemsetAsync(cnt_c, 0, (size_t)NCN*4, stream);
  (void)hipMemsetAsync(cur_c, 0, (size_t)NCN*4, stream);
  (void)hipMemsetAsync(cnt_v, 0, (size_t)NVN*4, stream);
  (void)hipMemsetAsync(cur_v, 0, (size_t)NVN*4, stream);

  k_fuse_w<<<64, 256, 0, stream>>>(wmsg, wupd, wf);
  k_fuse_b<<<1, 128, 0, stream>>>(bmsg, wupd, bfu);
  k_perm2<<<(H*H+255)/256, 256, 0, stream>>>(wf, wfph, wfpl, H);
  k_perm2<<<(H*H+255)/256, 256, 0, stream>>>(wc2v, wvph, wvpl, H);
  k_perm2<<<(2*H*H+255)/256, 256, 0, stream>>>(cgate_w, cgph, cgpl, 2*H);
  k_perm2<<<(2*H*H+255)/256, 256, 0, stream>>>(vgate_w, vgph, vgpl, 2*H);

  k_count<<<2048, 256, 0, stream>>>(evc_dst, ecv_dst, cnt_c, cnt_v);
  int nbc = (NCN + 255)/256, nbv = (NVN + 255)/256;
  k_scan1m<<<nbc + nbv, 256, 0, stream>>>(cnt_c, off_c, aux_c, nbc, NCN,
                                          cnt_v, off_v, aux_v, NVN);
  k_scan2m<<<2, 1024, 0, stream>>>(aux_c, nbc, aux_v, nbv);
  k_scan3m<<<nbc + nbv, 256, 0, stream>>>(off_c, aux_c, nbc, NCN,
                                          off_v, aux_v, NVN, NE);
  k_scatter<<<2048, 256, 0, stream>>>(evc_src, evc_dst, ecv_src, ecv_dst,
                                      off_c, cur_c, lst_c, off_v, cur_v, lst_v);

  k_init_var<<<NVN/4, 256, 0, stream>>>(x_var, vproj_w, vproj_b, var_ln_g, var_ln_b, hv, hvb);
  k_init_con<<<NCN/4, 256, 0, stream>>>(x_con, cproj_w, cproj_b, con_ln_g, con_ln_b, hc, hcb);

  for (int r = 0; r < 2; ++r) {
    // ---- v2c: gather(hvb)->t_c, then fused mm+LN+gate -> hc/hcb ----
    k_gather_bf<<<(NCN+3)/4, 256, 0, stream>>>((const unsigned int*)hvb, off_c, lst_c, t_c, NCN);
    k_mleg<0><<<(NCN+31)/32, 128, 0, stream>>>(t_c, wfph, wfpl, off_c, x_con, bfu, wupd + H*H,
                                               bupd, v2c_ln_g, v2c_ln_b, cgph, cgate_b,
                                               hc, hcb, NCN);
    // ---- c2v: gather(hcb)->t_v, then fused mm+LN+gate -> hv/hvb ----
    k_gather_bf<<<(NVN+3)/4, 256, 0, stream>>>((const unsigned int*)hcb, off_v, lst_v, t_v, NVN);
    k_mleg<1><<<(NVN+31)/32, 128, 0, stream>>>(t_v, wvph, wvpl, off_v, nullptr, bc2v, nullptr,
                                               nullptr, c2v_ln_g, c2v_ln_b, vgph, vgate_b,
                                               hv, hvb, NVN);
  }
}

// Round 19
// 583.225 us; speedup vs baseline: 1.0699x; 1.0091x over previous
//
#include <hip/hip_runtime.h>
#include <stdint.h>

#define NVN 100000
#define NCN 50000
#define NE  800000
#define H   128

typedef __attribute__((ext_vector_type(8))) short bf16x8;
typedef __attribute__((ext_vector_type(4))) float f32x4;

static __device__ __forceinline__ float wredsum(float v) {
#pragma unroll
  for (int off = 32; off > 0; off >>= 1) v += __shfl_xor(v, off, 64);
  return v;
}
static __device__ __forceinline__ float sigmoidf(float x) { return 1.0f / (1.0f + __expf(-x)); }
static __device__ __forceinline__ unsigned short f2bf(float f) {
  unsigned int u = __float_as_uint(f);
  return (unsigned short)((u + 0x7FFFu + ((u >> 16) & 1u)) >> 16);  // RNE
}
static __device__ __forceinline__ float bf2f(unsigned short u) {
  return __uint_as_float(((unsigned int)u) << 16);
}
static __device__ __forceinline__ short2 splitbf(float f) {
  unsigned short h = f2bf(f);
  float hf = bf2f(h);
  short2 r;
  r.x = (short)h;
  r.y = (short)f2bf(f - hf);
  return r;
}

// ---------------- init: h = LN(relu(x @ W + b)) -> bf16 shadow only (f32 master not needed) ----------------
__global__ __launch_bounds__(256) void k_init_var(const float* __restrict__ xv,
    const float* __restrict__ w, const float* __restrict__ b,
    const float* __restrict__ g, const float* __restrict__ bb,
    unsigned short* __restrict__ hb) {
  int wid = (blockIdx.x * 256 + threadIdx.x) >> 6;
  int lane = threadIdx.x & 63;
  if (wid >= NVN) return;
  float x0 = xv[wid*4+0], x1 = xv[wid*4+1], x2 = xv[wid*4+2], x3 = xv[wid*4+3];
  int c0 = lane, c1 = lane + 64;
  float v0 = b[c0] + x0*w[c0] + x1*w[H+c0] + x2*w[2*H+c0] + x3*w[3*H+c0];
  float v1 = b[c1] + x0*w[c1] + x1*w[H+c1] + x2*w[2*H+c1] + x3*w[3*H+c1];
  v0 = fmaxf(v0, 0.f); v1 = fmaxf(v1, 0.f);
  float mu = wredsum(v0 + v1) * (1.0f/H);
  float d0 = v0 - mu, d1 = v1 - mu;
  float var = wredsum(d0*d0 + d1*d1) * (1.0f/H);
  float r = rsqrtf(var + 1e-5f);
  float o0 = d0*r*g[c0] + bb[c0], o1 = d1*r*g[c1] + bb[c1];
  hb[(size_t)wid*H + c0] = f2bf(o0);  hb[(size_t)wid*H + c1] = f2bf(o1);
}

__global__ __launch_bounds__(256) void k_init_con(const float* __restrict__ xc,
    const float* __restrict__ w, const float* __restrict__ b,
    const float* __restrict__ g, const float* __restrict__ bb,
    unsigned short* __restrict__ hb) {
  int wid = (blockIdx.x * 256 + threadIdx.x) >> 6;
  int lane = threadIdx.x & 63;
  if (wid >= NCN) return;
  float x = xc[wid];
  int c0 = lane, c1 = lane + 64;
  float v0 = fmaxf(b[c0] + x*w[c0], 0.f);
  float v1 = fmaxf(b[c1] + x*w[c1], 0.f);
  float mu = wredsum(v0 + v1) * (1.0f/H);
  float d0 = v0 - mu, d1 = v1 - mu;
  float var = wredsum(d0*d0 + d1*d1) * (1.0f/H);
  float r = rsqrtf(var + 1e-5f);
  float o0 = d0*r*g[c0] + bb[c0], o1 = d1*r*g[c1] + bb[c1];
  hb[(size_t)wid*H + c0] = f2bf(o0);  hb[(size_t)wid*H + c1] = f2bf(o1);
}

// ---------------- weight fusion ----------------
__global__ void k_fuse_w(const float* __restrict__ wm, const float* __restrict__ wu,
                         float* __restrict__ wf) {
  int idx = blockIdx.x*256 + threadIdx.x;   // 16384
  int i = idx >> 7, j = idx & 127;
  float a = 0.f;
  for (int k = 0; k < H; ++k) a = fmaf(wm[i*H+k], wu[k*H+j], a);
  wf[idx] = a;
}
__global__ void k_fuse_b(const float* __restrict__ bm, const float* __restrict__ wu,
                         float* __restrict__ bf) {
  int j = threadIdx.x;
  float a = 0.f;
  for (int k = 0; k < H; ++k) a = fmaf(bm[k], wu[k*H+j], a);
  bf[j] = a;
}

// ---------------- weight permutation into MFMA B-fragment order, hi+lo split ----------------
__global__ __launch_bounds__(256) void k_perm2(const float* __restrict__ W,
    unsigned short* __restrict__ Whi, unsigned short* __restrict__ Wlo, int K) {
  int idx = blockIdx.x*256 + threadIdx.x;
  if (idx >= K*H) return;
  int j = idx & 7, lane = (idx >> 3) & 63, ct = (idx >> 9) & 7, kb = idx >> 12;
  int k = kb*32 + (lane >> 4)*8 + j, c = ct*16 + (lane & 15);
  float w = W[k*H + c];
  unsigned short h = f2bf(w);
  Whi[idx] = h;
  Wlo[idx] = f2bf(w - bf2f(h));
}

// ---------------- CSR build ----------------
__global__ void k_count(const int* __restrict__ dc, const int* __restrict__ dv,
                        int* __restrict__ cnt_c, int* __restrict__ cnt_v) {
  for (int e = blockIdx.x*blockDim.x + threadIdx.x; e < NE; e += gridDim.x*blockDim.x) {
    atomicAdd(&cnt_c[dc[e]], 1);
    atomicAdd(&cnt_v[dv[e]], 1);
  }
}
// merged c+v block scans: blocks [0,nbc) handle c, [nbc,nbc+nbv) handle v
__global__ __launch_bounds__(256) void k_scan1m(
    const int* __restrict__ in_c, int* __restrict__ out_c, int* __restrict__ aux_c, int nbc, int n_c,
    const int* __restrict__ in_v, int* __restrict__ out_v, int* __restrict__ aux_v, int n_v) {
  const int b = blockIdx.x;
  const int* in; int* out; int* aux; int n; int lb;
  if (b < nbc) { in = in_c; out = out_c; aux = aux_c; n = n_c; lb = b; }
  else         { in = in_v; out = out_v; aux = aux_v; n = n_v; lb = b - nbc; }
  __shared__ int s[256];
  int t = threadIdx.x, i = lb*256 + t;
  int v = (i < n) ? in[i] : 0;
  s[t] = v; __syncthreads();
  for (int off = 1; off < 256; off <<= 1) {
    int x = (t >= off) ? s[t - off] : 0;
    __syncthreads();
    s[t] += x;
    __syncthreads();
  }
  if (i < n) out[i] = s[t] - v;
  if (t == 255) aux[lb] = s[255];
}
__global__ __launch_bounds__(1024) void k_scan2m(int* __restrict__ aux_c, int nbc,
                                                 int* __restrict__ aux_v, int nbv) {
  int* aux = (blockIdx.x == 0) ? aux_c : aux_v;
  int nb   = (blockIdx.x == 0) ? nbc : nbv;
  __shared__ int s[1024];
  int t = threadIdx.x;
  int v = (t < nb) ? aux[t] : 0;
  s[t] = v; __syncthreads();
  for (int off = 1; off < 1024; off <<= 1) {
    int x = (t >= off) ? s[t-off] : 0;
    __syncthreads();
    s[t] += x;
    __syncthreads();
  }
  if (t < nb) aux[t] = s[t] - v;
}
__global__ __launch_bounds__(256) void k_scan3m(
    int* __restrict__ out_c, const int* __restrict__ aux_c, int nbc, int n_c,
    int* __restrict__ out_v, const int* __restrict__ aux_v, int n_v, int total) {
  const int b = blockIdx.x;
  int* out; const int* aux; int n; int lb;
  if (b < nbc) { out = out_c; aux = aux_c; n = n_c; lb = b; }
  else         { out = out_v; aux = aux_v; n = n_v; lb = b - nbc; }
  int i = lb*256 + threadIdx.x;
  if (i < n) out[i] += aux[lb];
  if (i == 0) out[n] = total;
}
// scatter (r15-proven): forward cursor + plain stores
__global__ void k_scatter(const int* __restrict__ sc, const int* __restrict__ dc,
                          const int* __restrict__ sv, const int* __restrict__ dv,
                          const int* __restrict__ off_c, int* __restrict__ cur_c, int* __restrict__ lst_c,
                          const int* __restrict__ off_v, int* __restrict__ cur_v, int* __restrict__ lst_v) {
  for (int e = blockIdx.x*blockDim.x + threadIdx.x; e < NE; e += gridDim.x*blockDim.x) {
    int d = dc[e]; int p = atomicAdd(&cur_c[d], 1); lst_c[off_c[d] + p] = sc[e];
    d = dv[e];     p = atomicAdd(&cur_v[d], 1);     lst_v[off_v[d] + p] = sv[e];
  }
}

// ---------------- lane-packed gather (r15-proven): 16 lanes/row-octet x 4 edge slots ----------------
__global__ __launch_bounds__(256) void k_gather_bf(const unsigned int* __restrict__ tab,
    const int* __restrict__ off, const int* __restrict__ lst,
    float* __restrict__ out, int n) {
  int wid = (blockIdx.x * 256 + threadIdx.x) >> 6;
  int lane = threadIdx.x & 63;
  if (wid >= n) return;
  int s0 = off[wid], s1 = off[wid+1];
  const int grp = lane >> 4, c16 = lane & 15;
  float acc[8];
#pragma unroll
  for (int j = 0; j < 8; ++j) acc[j] = 0.f;
#pragma unroll 2
  for (int p = s0 + grp; p < s1; p += 4) {
    int idx = lst[p];
    uint4 u = *(const uint4*)(tab + (size_t)idx*64 + c16*4);
    acc[0] += __uint_as_float(u.x << 16);
    acc[1] += __uint_as_float(u.x & 0xFFFF0000u);
    acc[2] += __uint_as_float(u.y << 16);
    acc[3] += __uint_as_float(u.y & 0xFFFF0000u);
    acc[4] += __uint_as_float(u.z << 16);
    acc[5] += __uint_as_float(u.z & 0xFFFF0000u);
    acc[6] += __uint_as_float(u.w << 16);
    acc[7] += __uint_as_float(u.w & 0xFFFF0000u);
  }
#pragma unroll
  for (int j = 0; j < 8; ++j) {
    acc[j] += __shfl_xor(acc[j], 16, 64);
    acc[j] += __shfl_xor(acc[j], 32, 64);
  }
  if (lane < 16) {
    float inv = 1.0f / ((float)(s1 - s0) + 1e-6f);
    float* op = out + (size_t)wid*H + c16*8;
    *(float4*)(op)     = make_float4(acc[0]*inv, acc[1]*inv, acc[2]*inv, acc[3]*inv);
    *(float4*)(op + 4) = make_float4(acc[4]*inv, acc[5]*inv, acc[6]*inv, acc[7]*inv);
  }
}

// ====== mega-fused, bf16-h recursion: matmul1 -> LDS park -> SIMT LN -> gate matmul2 -> blend ======
// h lives in bf16 (Hb) between rounds; f32 output written only when WRITEF (final var round).
// A1 (old h) is bf16-exact -> single MFMA per fragment for kb 0-3.
template<int EPI, int WRITEF>
__global__ __launch_bounds__(128) void k_mleg(
    const float* __restrict__ A,
    const unsigned short* __restrict__ Wph, const unsigned short* __restrict__ Wpl,
    const int* __restrict__ off, const float* __restrict__ xc,
    const float* __restrict__ vb, const float* __restrict__ wcl,
    const float* __restrict__ badd, const float* __restrict__ lng,
    const float* __restrict__ lnb,
    const unsigned short* __restrict__ Gph, const float* __restrict__ gb,
    unsigned short* __restrict__ Hb, float* __restrict__ HmOut, int n) {
  __shared__ float lds[32][132];               // 16.9KB park buffer
  const int wv = threadIdx.x >> 6, lane = threadIdx.x & 63;
  const int rbase = blockIdx.x*32 + wv*16;
  if (rbase >= n) return;
  const int g = lane >> 4, c15 = lane & 15;
  int arow = rbase + c15; if (arow > n-1) arow = n-1;

  // ---- prefetch A1 = Hb own rows (bf16, exact fragments) ----
  const unsigned short* Hbr = Hb + (size_t)arow*H + g*8;
  bf16x8 a1[4];
#pragma unroll
  for (int kb = 0; kb < 4; ++kb) a1[kb] = *(const bf16x8*)(Hbr + kb*32);

  // ---- matmul1: A @ W (split both operands, 3 MFMA) ----
  {
    const float* Ar = A + (size_t)arow*H + g*8;
    bf16x8 ahi[4], alo[4];
#pragma unroll
    for (int kb = 0; kb < 4; ++kb) {
      float4 p0 = *(const float4*)(Ar + kb*32);
      float4 p1 = *(const float4*)(Ar + kb*32 + 4);
      bf16x8 h, l;
      short2 s;
      s = splitbf(p0.x); h[0] = s.x; l[0] = s.y;
      s = splitbf(p0.y); h[1] = s.x; l[1] = s.y;
      s = splitbf(p0.z); h[2] = s.x; l[2] = s.y;
      s = splitbf(p0.w); h[3] = s.x; l[3] = s.y;
      s = splitbf(p1.x); h[4] = s.x; l[4] = s.y;
      s = splitbf(p1.y); h[5] = s.x; l[5] = s.y;
      s = splitbf(p1.z); h[6] = s.x; l[6] = s.y;
      s = splitbf(p1.w); h[7] = s.x; l[7] = s.y;
      ahi[kb] = h; alo[kb] = l;
    }
    const bf16x8* Bph = (const bf16x8*)Wph;
    const bf16x8* Bpl = (const bf16x8*)Wpl;
    f32x4 zero = {0.f, 0.f, 0.f, 0.f};
    f32x4 acc[8];
#pragma unroll
    for (int ct = 0; ct < 8; ++ct) acc[ct] = zero;
#pragma unroll
    for (int kb = 0; kb < 4; ++kb)
#pragma unroll
      for (int ct = 0; ct < 8; ++ct) {
        bf16x8 bh = Bph[(kb*8+ct)*64 + lane];
        bf16x8 bl = Bpl[(kb*8+ct)*64 + lane];
        acc[ct] = __builtin_amdgcn_mfma_f32_16x16x32_bf16(ahi[kb], bh, acc[ct], 0, 0, 0);
        acc[ct] = __builtin_amdgcn_mfma_f32_16x16x32_bf16(alo[kb], bh, acc[ct], 0, 0, 0);
        acc[ct] = __builtin_amdgcn_mfma_f32_16x16x32_bf16(ahi[kb], bl, acc[ct], 0, 0, 0);
      }
    // park pre-activation into LDS (wave-local rows)
#pragma unroll
    for (int r = 0; r < 4; ++r)
#pragma unroll
      for (int ct = 0; ct < 8; ++ct)
        lds[wv*16 + g*4 + r][ct*16 + c15] = acc[ct][r];
  }

  // ---- proven SIMT LN epilogue; full blocks fully unrolled ----
  {
    float vb0 = vb[lane], vb1 = vb[lane+64];
    float lg0 = lng[lane], lg1 = lng[lane+64];
    float lb0 = lnb[lane], lb1 = lnb[lane+64];
    float wc0 = 0.f, wc1 = 0.f, ba0 = 0.f, ba1 = 0.f;
    if constexpr (EPI == 0) {
      wc0 = wcl[lane]; wc1 = wcl[lane+64];
      ba0 = badd[lane]; ba1 = badd[lane+64];
    }
    auto lnrow = [&](int row, int dst) {
      float cf = (float)(off[dst+1] - off[dst]);
      float scale = cf / (cf + 1e-6f);
      float v0 = lds[row][lane]     + scale*vb0;
      float v1 = lds[row][lane+64]  + scale*vb1;
      if constexpr (EPI == 0) {
        float clue = xc[dst];
        v0 += clue*wc0 + ba0;
        v1 += clue*wc1 + ba1;
      }
      v0 = fmaxf(v0, 0.f); v1 = fmaxf(v1, 0.f);
      float mu = wredsum(v0 + v1) * (1.0f/H);
      float d0 = v0 - mu, d1 = v1 - mu;
      float var = wredsum(d0*d0 + d1*d1) * (1.0f/H);
      float r = rsqrtf(var + 1e-5f);
      lds[row][lane]      = d0*r*lg0 + lb0;
      lds[row][lane + 64] = d1*r*lg1 + lb1;
    };
    const int blk = blockIdx.x*32;
    if (blk + 32 <= n) {
#pragma unroll
      for (int i = 0; i < 16; ++i) lnrow(wv*16 + i, blk + wv*16 + i);
    } else {
      for (int i = 0; i < 16; ++i) {
        int dst = blk + wv*16 + i;
        if (dst >= n) break;
        lnrow(wv*16 + i, dst);
      }
    }
  }

  // ---- matmul2: [Hb(bf16) | c_new(LDS, split)] @ G (B hi-only) + sigmoid gate + bf16 blend ----
  {
    bf16x8 chi[4], clo[4];
    const float* Ar2 = &lds[wv*16 + c15][0];               // c_new (LDS, own wave rows)
#pragma unroll
    for (int i = 0; i < 4; ++i) {
      float4 p0 = *(const float4*)(Ar2 + i*32 + g*8);
      float4 p1 = *(const float4*)(Ar2 + i*32 + g*8 + 4);
      bf16x8 h, l;
      short2 s;
      s = splitbf(p0.x); h[0] = s.x; l[0] = s.y;
      s = splitbf(p0.y); h[1] = s.x; l[1] = s.y;
      s = splitbf(p0.z); h[2] = s.x; l[2] = s.y;
      s = splitbf(p0.w); h[3] = s.x; l[3] = s.y;
      s = splitbf(p1.x); h[4] = s.x; l[4] = s.y;
      s = splitbf(p1.y); h[5] = s.x; l[5] = s.y;
      s = splitbf(p1.z); h[6] = s.x; l[6] = s.y;
      s = splitbf(p1.w); h[7] = s.x; l[7] = s.y;
      chi[i] = h; clo[i] = l;
    }
    const bf16x8* Bph = (const bf16x8*)Gph;
    f32x4 zero = {0.f, 0.f, 0.f, 0.f};
    f32x4 acc[8];
#pragma unroll
    for (int ct = 0; ct < 8; ++ct) acc[ct] = zero;
#pragma unroll
    for (int kb = 0; kb < 4; ++kb)
#pragma unroll
      for (int ct = 0; ct < 8; ++ct)
        acc[ct] = __builtin_amdgcn_mfma_f32_16x16x32_bf16(a1[kb], Bph[(kb*8+ct)*64 + lane], acc[ct], 0, 0, 0);
#pragma unroll
    for (int kb = 4; kb < 8; ++kb)
#pragma unroll
      for (int ct = 0; ct < 8; ++ct) {
        bf16x8 bh = Bph[(kb*8+ct)*64 + lane];
        acc[ct] = __builtin_amdgcn_mfma_f32_16x16x32_bf16(chi[kb-4], bh, acc[ct], 0, 0, 0);
        acc[ct] = __builtin_amdgcn_mfma_f32_16x16x32_bf16(clo[kb-4], bh, acc[ct], 0, 0, 0);
      }
    float gbv[8];
#pragma unroll
    for (int ct = 0; ct < 8; ++ct) gbv[ct] = gb[ct*16 + c15];
#pragma unroll
    for (int r = 0; r < 4; ++r) {
      int rg = rbase + g*4 + r;
      if (rg >= n) continue;
      int row = wv*16 + g*4 + r;
      unsigned short* hbp = Hb + (size_t)rg*H + c15;
      float* hop = HmOut + (size_t)rg*H + c15;
#pragma unroll
      for (int ct = 0; ct < 8; ++ct) {
        float gg = sigmoidf(acc[ct][r] + gbv[ct]);
        float nv = lds[row][ct*16 + c15];
        float ov = bf2f(hbp[ct*16]);
        float res = gg*nv + (1.f - gg)*ov;
        hbp[ct*16] = f2bf(res);
        if constexpr (WRITEF) hop[ct*16] = res;
      }
    }
  }
}

extern "C" void kernel_launch(void* const* d_in, const int* in_sizes, int n_in,
                              void* d_out, int out_size, void* d_ws, size_t ws_size,
                              hipStream_t stream) {
  const float* x_var   = (const float*)d_in[0];
  const float* x_con   = (const float*)d_in[1];
  const int*   evc_src = (const int*)d_in[2];
  const int*   evc_dst = (const int*)d_in[3];
  const int*   ecv_src = (const int*)d_in[4];
  const int*   ecv_dst = (const int*)d_in[5];
  const float* vproj_w = (const float*)d_in[6];
  const float* vproj_b = (const float*)d_in[7];
  const float* cproj_w = (const float*)d_in[8];
  const float* cproj_b = (const float*)d_in[9];
  const float* wmsg    = (const float*)d_in[10];
  const float* bmsg    = (const float*)d_in[11];
  const float* wupd    = (const float*)d_in[12];
  const float* bupd    = (const float*)d_in[13];
  const float* v2c_ln_g = (const float*)d_in[14];
  const float* v2c_ln_b = (const float*)d_in[15];
  const float* wc2v    = (const float*)d_in[16];
  const float* bc2v    = (const float*)d_in[17];
  const float* c2v_ln_g = (const float*)d_in[18];
  const float* c2v_ln_b = (const float*)d_in[19];
  const float* vgate_w = (const float*)d_in[20];
  const float* vgate_b = (const float*)d_in[21];
  const float* cgate_w = (const float*)d_in[22];
  const float* cgate_b = (const float*)d_in[23];
  const float* var_ln_g = (const float*)d_in[24];
  const float* var_ln_b = (const float*)d_in[25];
  const float* con_ln_g = (const float*)d_in[26];
  const float* con_ln_b = (const float*)d_in[27];
  float* hv = (float*)d_out;

  char* p = (char*)d_ws;
  auto carve = [&](size_t bytes) { char* r = p; p += (bytes + 255) & ~(size_t)255; return r; };
  int* cnt_c = (int*)carve((size_t)NCN*4);
  int* cur_c = (int*)carve((size_t)NCN*4);
  int* cnt_v = (int*)carve((size_t)NVN*4);
  int* cur_v = (int*)carve((size_t)NVN*4);
  int* off_c = (int*)carve((size_t)(NCN+1)*4);
  int* off_v = (int*)carve((size_t)(NVN+1)*4);
  int* aux_c = (int*)carve(1024*4);
  int* aux_v = (int*)carve(1024*4);
  int* lst_c = (int*)carve((size_t)NE*4);
  int* lst_v = (int*)carve((size_t)NE*4);
  float* wf  = (float*)carve((size_t)H*H*4);
  float* bfu = (float*)carve((size_t)H*4);
  unsigned short* wfph = (unsigned short*)carve((size_t)H*H*2);
  unsigned short* wfpl = (unsigned short*)carve((size_t)H*H*2);
  unsigned short* wvph = (unsigned short*)carve((size_t)H*H*2);
  unsigned short* wvpl = (unsigned short*)carve((size_t)H*H*2);
  unsigned short* cgph = (unsigned short*)carve((size_t)2*H*H*2);
  unsigned short* cgpl = (unsigned short*)carve((size_t)2*H*H*2);
  unsigned short* vgph = (unsigned short*)carve((size_t)2*H*H*2);
  unsigned short* vgpl = (unsigned short*)carve((size_t)2*H*H*2);
  float* t_c   = (float*)carve((size_t)NCN*H*4);
  float* t_v   = (float*)carve((size_t)NVN*H*4);
  unsigned short* hvb = (unsigned short*)carve((size_t)NVN*H*2);
  unsigned short* hcb = (unsigned short*)carve((size_t)NCN*H*2);
  if ((size_t)(p - (char*)d_ws) > ws_size) return;

  (void)hipMemsetAsync(cnt_c, 0, (size_t)NCN*4, stream);
  (void)hipMemsetAsync(cur_c, 0, (size_t)NCN*4, stream);
  (void)hipMemsetAsync(cnt_v, 0, (size_t)NVN*4, stream);
  (void)hipMemsetAsync(cur_v, 0, (size_t)NVN*4, stream);

  k_fuse_w<<<64, 256, 0, stream>>>(wmsg, wupd, wf);
  k_fuse_b<<<1, 128, 0, stream>>>(bmsg, wupd, bfu);
  k_perm2<<<(H*H+255)/256, 256, 0, stream>>>(wf, wfph, wfpl, H);
  k_perm2<<<(H*H+255)/256, 256, 0, stream>>>(wc2v, wvph, wvpl, H);
  k_perm2<<<(2*H*H+255)/256, 256, 0, stream>>>(cgate_w, cgph, cgpl, 2*H);
  k_perm2<<<(2*H*H+255)/256, 256, 0, stream>>>(vgate_w, vgph, vgpl, 2*H);

  k_count<<<2048, 256, 0, stream>>>(evc_dst, ecv_dst, cnt_c, cnt_v);
  int nbc = (NCN + 255)/256, nbv = (NVN + 255)/256;
  k_scan1m<<<nbc + nbv, 256, 0, stream>>>(cnt_c, off_c, aux_c, nbc, NCN,
                                          cnt_v, off_v, aux_v, NVN);
  k_scan2m<<<2, 1024, 0, stream>>>(aux_c, nbc, aux_v, nbv);
  k_scan3m<<<nbc + nbv, 256, 0, stream>>>(off_c, aux_c, nbc, NCN,
                                          off_v, aux_v, NVN, NE);
  k_scatter<<<2048, 256, 0, stream>>>(evc_src, evc_dst, ecv_src, ecv_dst,
                                      off_c, cur_c, lst_c, off_v, cur_v, lst_v);

  k_init_var<<<NVN/4, 256, 0, stream>>>(x_var, vproj_w, vproj_b, var_ln_g, var_ln_b, hvb);
  k_init_con<<<NCN/4, 256, 0, stream>>>(x_con, cproj_w, cproj_b, con_ln_g, con_ln_b, hcb);

  // ---- round 0 ----
  k_gather_bf<<<(NCN+3)/4, 256, 0, stream>>>((const unsigned int*)hvb, off_c, lst_c, t_c, NCN);
  k_mleg<0,0><<<(NCN+31)/32, 128, 0, stream>>>(t_c, wfph, wfpl, off_c, x_con, bfu, wupd + H*H,
                                               bupd, v2c_ln_g, v2c_ln_b, cgph, cgate_b,
                                               hcb, hv, NCN);
  k_gather_bf<<<(NVN+3)/4, 256, 0, stream>>>((const unsigned int*)hcb, off_v, lst_v, t_v, NVN);
  k_mleg<1,0><<<(NVN+31)/32, 128, 0, stream>>>(t_v, wvph, wvpl, off_v, nullptr, bc2v, nullptr,
                                               nullptr, c2v_ln_g, c2v_ln_b, vgph, vgate_b,
                                               hvb, hv, NVN);
  // ---- round 1 (final: var side writes f32 output) ----
  k_gather_bf<<<(NCN+3)/4, 256, 0, stream>>>((const unsigned int*)hvb, off_c, lst_c, t_c, NCN);
  k_mleg<0,0><<<(NCN+31)/32, 128, 0, stream>>>(t_c, wfph, wfpl, off_c, x_con, bfu, wupd + H*H,
                                               bupd, v2c_ln_g, v2c_ln_b, cgph, cgate_b,
                                               hcb, hv, NCN);
  k_gather_bf<<<(NVN+3)/4, 256, 0, stream>>>((const unsigned int*)hcb, off_v, lst_v, t_v, NVN);
  k_mleg<1,1><<<(NVN+31)/32, 128, 0, stream>>>(t_v, wvph, wvpl, off_v, nullptr, bc2v, nullptr,
                                               nullptr, c2v_ln_g, c2v_ln_b, vgph, vgate_b,
                                               hvb, hv, NVN);
}